// Round 6
// baseline (1073.307 us; speedup 1.0000x reference)
//
#include <hip/hip_runtime.h>
#include <cstdint>

typedef short short8 __attribute__((ext_vector_type(8)));
typedef float floatx4 __attribute__((ext_vector_type(4)));

constexpr int NU = 200000;   // N_USER
constexpr int NI = 100000;   // N_ITEM
constexpr int NEDGE = 1000000;
constexpr int HD = 128;
constexpr int HH = HD * HD;

// ---- bf16 bit helpers ----
__device__ __forceinline__ float bits2f(short s) {
    return __uint_as_float(((unsigned int)(unsigned short)s) << 16);
}
__device__ __forceinline__ short f2bits(float f) {
    unsigned int u = __float_as_uint(f);
    unsigned int lsb = (u >> 16) & 1u;
    u += 0x7fffu + lsb;   // round-to-nearest-even
    return (short)(u >> 16);
}

// ================= CSR build =================
// merged histogram over all 3 graphs (one launch, overlapped latency)
__global__ void k_hist3(const int* __restrict__ dst0, const int* __restrict__ dst1,
                        const int* __restrict__ dst2, int* __restrict__ deg0,
                        int* __restrict__ deg1, int* __restrict__ deg2, int E) {
    int i = blockIdx.x * 256 + threadIdx.x;
    if (i < E) atomicAdd(&deg0[dst0[i]], 1);
    else if (i < 2 * E) atomicAdd(&deg1[dst1[i - E]], 1);
    else if (i < 3 * E) atomicAdd(&deg2[dst2[i - 2 * E]], 1);
}

__global__ void k_block_sums(const int* __restrict__ deg, int* __restrict__ bsum, int N) {
    __shared__ int s[1024];
    int t = threadIdx.x;
    int i = blockIdx.x * 1024 + t;
    s[t] = (i < N) ? deg[i] : 0;
    __syncthreads();
    for (int d = 512; d > 0; d >>= 1) {
        if (t < d) s[t] += s[t + d];
        __syncthreads();
    }
    if (t == 0) bsum[blockIdx.x] = s[0];
}

__global__ void k_scan_bsums(const int* __restrict__ bsum, int* __restrict__ boff,
                             int* __restrict__ off, int nb, int N) {
    __shared__ int s[1024];
    int t = threadIdx.x;
    int v = (t < nb) ? bsum[t] : 0;
    s[t] = v;
    __syncthreads();
    for (int d = 1; d < 1024; d <<= 1) {
        int u = (t >= d) ? s[t - d] : 0;
        __syncthreads();
        s[t] += u;
        __syncthreads();
    }
    if (t < nb) boff[t] = s[t] - v;     // exclusive block offsets
    if (t == nb - 1) off[N] = s[t];     // total
}

__global__ void k_scan_write(const int* __restrict__ deg, const int* __restrict__ boff,
                             int* __restrict__ off, int N) {
    __shared__ int s[1024];
    int t = threadIdx.x;
    int i = blockIdx.x * 1024 + t;
    int v = (i < N) ? deg[i] : 0;
    s[t] = v;
    __syncthreads();
    for (int d = 1; d < 1024; d <<= 1) {
        int u = (t >= d) ? s[t - d] : 0;
        __syncthreads();
        s[t] += u;
        __syncthreads();
    }
    if (i < N) off[i] = boff[blockIdx.x] + s[t] - v;
}

// merged low-contention scatter fill over all 3 graphs (one launch).
// k_fill was latency/line-pingpong bound at 12.6% HBM; interleaving three
// independent streams overlaps the stalls.
__global__ void k_fill3(const int* __restrict__ src0, const int* __restrict__ dst0,
                        int* __restrict__ cur0, int* __restrict__ esrc0,
                        const int* __restrict__ src1, const int* __restrict__ dst1,
                        int* __restrict__ cur1, int* __restrict__ esrc1,
                        const int* __restrict__ src2, const int* __restrict__ dst2,
                        int* __restrict__ cur2, int* __restrict__ esrc2, int E) {
    int i = blockIdx.x * 256 + threadIdx.x;
    if (i < E) {
        int pos = atomicAdd(&cur0[dst0[i]], 1);
        esrc0[pos] = src0[i];
    } else if (i < 2 * E) {
        i -= E;
        int pos = atomicAdd(&cur1[dst1[i]], 1);
        esrc1[pos] = src1[i];
    } else if (i < 3 * E) {
        i -= 2 * E;
        int pos = atomicAdd(&cur2[dst2[i]], 1);
        esrc2[pos] = src2[i];
    }
}

// ================= weight pack (fp32 -> bf16 fragment order) =================
__global__ void k_pack(short* __restrict__ dst, const float* __restrict__ A,
                       const float* __restrict__ B, const float* __restrict__ B2,
                       int KA, int KBr, int NCOL) {
    int l = threadIdx.x;
    int kbt = (KA + KBr) >> 5;
    int nt = blockIdx.x / kbt;
    int kb = blockIdx.x % kbt;
    int col = nt * 16 + (l & 15);
    int k0 = kb * 32 + (l >> 4) * 8;
    short8 o;
#pragma unroll
    for (int j = 0; j < 8; ++j) {
        int k = k0 + j;
        float f;
        if (k < KA) {
            f = A[(size_t)k * NCOL + col];
        } else {
            int k2 = k - KA;
            f = B[(size_t)k2 * NCOL + col];
            if (B2) f += B2[(size_t)k2 * NCOL + col];
        }
        o[j] = f2bits(f);
    }
    *(short8*)(dst + ((size_t)blockIdx.x * 64 + l) * 8) = o;
}

__global__ void k_addbias(float* __restrict__ dst, const float* __restrict__ a,
                          const float* __restrict__ b) {
    int i = threadIdx.x;
    dst[i] = a[i] + b[i];
}

// ================= fused SAGE: gather-mean + MFMA GEMM =================
// C[M,128] = mean_{nbr} Xsrc[nbr] @ Wl  (+ A2 @ Wr)  (+bias) (+=C) (leaky)
// Edge loop unrolled x4: 16 row-loads in flight per lane (was 4) -> ~4x MLP
// for the latency-bound gather (r5 counters: Mfma 2.3%, VALU 20%, HBM 23%).
template <int KB2, bool ACCUM, bool LEAKY>
__global__ __launch_bounds__(256) void k_sage(const short* __restrict__ Xsrc,
                                              const short* __restrict__ A2,
                                              const int* __restrict__ off,
                                              const int* __restrict__ esrc,
                                              const short* __restrict__ Wp,
                                              const float* __restrict__ bias,
                                              short* __restrict__ C, int M) {
    constexpr int KBT = 4 + KB2;   // gather side is always K=128 (4 kb)
    const int lane = threadIdx.x & 63;
    const int wv = threadIdx.x >> 6;
    const int r0 = blockIdx.x * 64 + wv * 16;

    int ar = r0 + (lane & 15);
    if (ar >= M) ar = M - 1;       // clamp: only pollutes masked-out C rows
    const int ksub = (lane >> 4) * 8;

    float macc[4][8];
#pragma unroll
    for (int kb = 0; kb < 4; ++kb)
#pragma unroll
        for (int i = 0; i < 8; ++i) macc[kb][i] = 0.f;

    const int s = off[ar], e = off[ar + 1];
    int j = s;
    for (; j + 4 <= e; j += 4) {
        const int i0 = esrc[j], i1 = esrc[j + 1], i2 = esrc[j + 2], i3 = esrc[j + 3];
        const short* p0 = Xsrc + (size_t)i0 * HD + ksub;
        const short* p1 = Xsrc + (size_t)i1 * HD + ksub;
        const short* p2 = Xsrc + (size_t)i2 * HD + ksub;
        const short* p3 = Xsrc + (size_t)i3 * HD + ksub;
        short8 v0[4], v1[4], v2[4], v3[4];
#pragma unroll
        for (int kb = 0; kb < 4; ++kb) {
            v0[kb] = *(const short8*)(p0 + kb * 32);
            v1[kb] = *(const short8*)(p1 + kb * 32);
            v2[kb] = *(const short8*)(p2 + kb * 32);
            v3[kb] = *(const short8*)(p3 + kb * 32);
        }
#pragma unroll
        for (int kb = 0; kb < 4; ++kb)
#pragma unroll
            for (int i = 0; i < 8; ++i)
                macc[kb][i] += (bits2f(v0[kb][i]) + bits2f(v1[kb][i]))
                             + (bits2f(v2[kb][i]) + bits2f(v3[kb][i]));
    }
    for (; j < e; ++j) {
        const short* xp = Xsrc + (size_t)esrc[j] * HD + ksub;
#pragma unroll
        for (int kb = 0; kb < 4; ++kb) {
            short8 v = *(const short8*)(xp + kb * 32);
#pragma unroll
            for (int i = 0; i < 8; ++i) macc[kb][i] += bits2f(v[i]);
        }
    }
    const int d = e - s;
    const float inv = 1.f / (float)(d > 0 ? d : 1);

    short8 afrag[KBT];
#pragma unroll
    for (int kb = 0; kb < 4; ++kb) {
        short8 f;
#pragma unroll
        for (int i = 0; i < 8; ++i) f[i] = f2bits(macc[kb][i] * inv);
        afrag[kb] = f;
    }
    if constexpr (KB2 > 0) {
        const short* p = A2 + (size_t)ar * (KB2 * 32) + ksub;
#pragma unroll
        for (int kb = 0; kb < KB2; ++kb) afrag[4 + kb] = *(const short8*)(p + kb * 32);
    }

    floatx4 acc[8];
#pragma unroll
    for (int nt = 0; nt < 8; ++nt) acc[nt] = (floatx4){0.f, 0.f, 0.f, 0.f};

    const short8* wp = (const short8*)Wp + lane;
#pragma unroll
    for (int nt = 0; nt < 8; ++nt) {
#pragma unroll
        for (int kb = 0; kb < KBT; ++kb) {
            short8 b = wp[(nt * KBT + kb) * 64];
            acc[nt] = __builtin_amdgcn_mfma_f32_16x16x32_bf16(afrag[kb], b, acc[nt], 0, 0, 0);
        }
    }

    const int col = lane & 15;
    const int rbase = r0 + (lane >> 4) * 4;
#pragma unroll
    for (int nt = 0; nt < 8; ++nt) {
        float bv = bias ? bias[nt * 16 + col] : 0.f;
#pragma unroll
        for (int r = 0; r < 4; ++r) {
            int row = rbase + r;
            if (row < M) {
                short* cp = C + (size_t)row * HD + nt * 16 + col;
                float v = acc[nt][r] + bv;
                if constexpr (ACCUM) v += bits2f(*cp);
                if constexpr (LEAKY) v = (v >= 0.f) ? v : 0.01f * v;
                *cp = f2bits(v);
            }
        }
    }
}

// ================= plain MFMA GEMM v2 (proj/head): 32 rows/wave =================
template <int KB1, bool AF32, bool OUTF32, int NT>
__global__ __launch_bounds__(256) void k_mm(const void* __restrict__ A1v,
                                            const short* __restrict__ Wp,
                                            const float* __restrict__ bias,
                                            void* __restrict__ Cv, int M) {
    constexpr int KBT = KB1;
    const int lane = threadIdx.x & 63;
    const int wv = threadIdx.x >> 6;
    const int r0 = blockIdx.x * 128 + wv * 32;

    const int ksub = (lane >> 4) * 8;
    short8 afrag[2][KBT];
#pragma unroll
    for (int h = 0; h < 2; ++h) {
        int ar = r0 + h * 16 + (lane & 15);
        if (ar >= M) ar = M - 1;
        if constexpr (AF32) {
            const float* p = (const float*)A1v + (size_t)ar * (KB1 * 32) + ksub;
#pragma unroll
            for (int kb = 0; kb < KB1; ++kb) {
                short8 f;
#pragma unroll
                for (int j = 0; j < 8; ++j) f[j] = f2bits(p[kb * 32 + j]);
                afrag[h][kb] = f;
            }
        } else {
            const short* p = (const short*)A1v + (size_t)ar * (KB1 * 32) + ksub;
#pragma unroll
            for (int kb = 0; kb < KB1; ++kb) afrag[h][kb] = *(const short8*)(p + kb * 32);
        }
    }

    floatx4 acc[2][NT];
#pragma unroll
    for (int h = 0; h < 2; ++h)
#pragma unroll
        for (int nt = 0; nt < NT; ++nt) acc[h][nt] = (floatx4){0.f, 0.f, 0.f, 0.f};

    const short8* wp = (const short8*)Wp + lane;
#pragma unroll
    for (int nt = 0; nt < NT; ++nt) {
#pragma unroll
        for (int kb = 0; kb < KBT; ++kb) {
            short8 b = wp[(nt * KBT + kb) * 64];
            acc[0][nt] = __builtin_amdgcn_mfma_f32_16x16x32_bf16(afrag[0][kb], b, acc[0][nt], 0, 0, 0);
            acc[1][nt] = __builtin_amdgcn_mfma_f32_16x16x32_bf16(afrag[1][kb], b, acc[1][nt], 0, 0, 0);
        }
    }

    const int col = lane & 15;
#pragma unroll
    for (int h = 0; h < 2; ++h) {
        const int rbase = r0 + h * 16 + (lane >> 4) * 4;
#pragma unroll
        for (int nt = 0; nt < NT; ++nt) {
            float bv = bias ? bias[nt * 16 + col] : 0.f;
#pragma unroll
            for (int r = 0; r < 4; ++r) {
                int row = rbase + r;
                if (row < M) {
                    float v = acc[h][nt][r] + bv;
                    if constexpr (OUTF32) {
                        ((float*)Cv)[(size_t)row * (NT * 16) + nt * 16 + col] = v;
                    } else {
                        ((short*)Cv)[(size_t)row * (NT * 16) + nt * 16 + col] = f2bits(v);
                    }
                }
            }
        }
    }
}

// ================= launch =================
extern "C" void kernel_launch(void* const* d_in, const int* in_sizes, int n_in,
                              void* d_out, int out_size, void* d_ws, size_t ws_size,
                              hipStream_t stream) {
    const float* x_user    = (const float*)d_in[0];
    const float* x_item    = (const float*)d_in[1];
    const int* src_rates   = (const int*)d_in[2];
    const int* dst_rates   = (const int*)d_in[3];
    const int* src_rated   = (const int*)d_in[4];
    const int* dst_rated   = (const int*)d_in[5];
    const int* src_fol     = (const int*)d_in[6];
    const int* dst_fol     = (const int*)d_in[7];
    const float* W_in_user = (const float*)d_in[8];
    const float* b_in_user = (const float*)d_in[9];
    const float* W_in_item = (const float*)d_in[10];
    const float* b_in_item = (const float*)d_in[11];
    const float* Wl_rates  = (const float*)d_in[12];
    const float* bl_rates  = (const float*)d_in[13];
    const float* Wr_rates  = (const float*)d_in[14];
    const float* Wl_rated  = (const float*)d_in[15];
    const float* bl_rated  = (const float*)d_in[16];
    const float* Wr_rated  = (const float*)d_in[17];
    const float* Wl_fol    = (const float*)d_in[18];
    const float* bl_fol    = (const float*)d_in[19];
    const float* Wr_fol    = (const float*)d_in[20];
    const float* W_out     = (const float*)d_in[21];
    const float* b_out     = (const float*)d_in[22];
    float* out = (float*)d_out;

    char* w = (char*)d_ws;
    size_t used = 0;
    auto alloc = [&](size_t bytes) -> void* {
        void* p = w + used;
        used += (bytes + 255) & ~(size_t)255;
        return p;
    };
    short* hu_a = (short*)alloc((size_t)NU * HD * 2);
    short* hu_b = (short*)alloc((size_t)NU * HD * 2);
    short* hi_a = (short*)alloc((size_t)NI * HD * 2);
    short* hi_b = (short*)alloc((size_t)NI * HD * 2);

    int* deg_rates  = (int*)alloc((size_t)NI * 4);
    int* off_rates  = (int*)alloc((size_t)(NI + 1) * 4);
    int* cur_rates  = (int*)alloc((size_t)NI * 4);
    int* esrc_rates = (int*)alloc((size_t)NEDGE * 4);
    int* deg_rated  = (int*)alloc((size_t)NU * 4);
    int* off_rated  = (int*)alloc((size_t)(NU + 1) * 4);
    int* cur_rated  = (int*)alloc((size_t)NU * 4);
    int* esrc_rated = (int*)alloc((size_t)NEDGE * 4);
    int* deg_fol    = (int*)alloc((size_t)NU * 4);
    int* off_fol    = (int*)alloc((size_t)(NU + 1) * 4);
    int* cur_fol    = (int*)alloc((size_t)NU * 4);
    int* esrc_fol   = (int*)alloc((size_t)NEDGE * 4);
    int* bsum = (int*)alloc(1024 * 4);
    int* boff = (int*)alloc(1024 * 4);

    short* pWu      = (short*)alloc(8 * 2 * 64 * 8 * 2);
    short* pWi      = (short*)alloc(8 * 4 * 64 * 8 * 2);
    short* pRates0  = (short*)alloc(8 * 8 * 64 * 8 * 2);
    short* pRates1  = (short*)alloc(8 * 8 * 64 * 8 * 2);
    short* pRated0  = (short*)alloc(8 * 8 * 64 * 8 * 2);
    short* pRated1  = (short*)alloc(8 * 8 * 64 * 8 * 2);
    short* pFol0    = (short*)alloc(8 * 4 * 64 * 8 * 2);
    short* pFol1    = (short*)alloc(8 * 4 * 64 * 8 * 2);
    short* pHead    = (short*)alloc(1 * 4 * 64 * 8 * 2);
    float* bSum0    = (float*)alloc(128 * 4);
    float* bSum1    = (float*)alloc(128 * 4);
    if (used > ws_size) return;   // diagnostic signature: output stays zero

    // ---- CSR build: merged hists, per-graph scans, merged fill ----
    hipMemsetAsync(deg_rates, 0, (size_t)NI * 4, stream);
    hipMemsetAsync(deg_rated, 0, (size_t)NU * 4, stream);
    hipMemsetAsync(deg_fol,   0, (size_t)NU * 4, stream);
    k_hist3<<<(3 * NEDGE + 255) / 256, 256, 0, stream>>>(
        dst_rates, dst_rated, dst_fol, deg_rates, deg_rated, deg_fol, NEDGE);

    auto scan = [&](int* deg, int* off, int* cur, int N) {
        int nb = (N + 1023) / 1024;
        k_block_sums<<<nb, 1024, 0, stream>>>(deg, bsum, N);
        k_scan_bsums<<<1, 1024, 0, stream>>>(bsum, boff, off, nb, N);
        k_scan_write<<<nb, 1024, 0, stream>>>(deg, boff, off, N);
        hipMemcpyAsync(cur, off, (size_t)N * 4, hipMemcpyDeviceToDevice, stream);
    };
    scan(deg_rates, off_rates, cur_rates, NI);
    scan(deg_rated, off_rated, cur_rated, NU);
    scan(deg_fol,   off_fol,   cur_fol,   NU);

    k_fill3<<<(3 * NEDGE + 255) / 256, 256, 0, stream>>>(
        src_rates, dst_rates, cur_rates, esrc_rates,
        src_rated, dst_rated, cur_rated, esrc_rated,
        src_fol,   dst_fol,   cur_fol,   esrc_fol, NEDGE);

    // ---- weight packing ----
    k_pack<<<16, 64, 0, stream>>>(pWu, W_in_user, nullptr, nullptr, 64, 0, 128);
    k_pack<<<32, 64, 0, stream>>>(pWi, W_in_item, nullptr, nullptr, 128, 0, 128);
    k_pack<<<64, 64, 0, stream>>>(pRates0, Wl_rates,      Wr_rates,      nullptr,       128, 128, 128);
    k_pack<<<64, 64, 0, stream>>>(pRates1, Wl_rates + HH, Wr_rates + HH, nullptr,       128, 128, 128);
    k_pack<<<64, 64, 0, stream>>>(pRated0, Wl_rated,      Wr_rated,      Wr_fol,        128, 128, 128);
    k_pack<<<64, 64, 0, stream>>>(pRated1, Wl_rated + HH, Wr_rated + HH, Wr_fol + HH,   128, 128, 128);
    k_pack<<<32, 64, 0, stream>>>(pFol0, Wl_fol,      nullptr, nullptr, 128, 0, 128);
    k_pack<<<32, 64, 0, stream>>>(pFol1, Wl_fol + HH, nullptr, nullptr, 128, 0, 128);
    k_pack<<<4, 64, 0, stream>>>(pHead, W_out, nullptr, nullptr, 128, 0, 16);
    k_addbias<<<1, 128, 0, stream>>>(bSum0, bl_rated,       bl_fol);
    k_addbias<<<1, 128, 0, stream>>>(bSum1, bl_rated + 128, bl_fol + 128);

    const int gU2 = (NU + 127) / 128;  // k_mm v2 grids
    const int gI2 = (NI + 127) / 128;
    const int gU  = (NU + 63) / 64;    // k_sage grids
    const int gI  = (NI + 63) / 64;

    // ---- input projections (fp32 A) ----
    k_mm<2, true, false, 8><<<gU2, 256, 0, stream>>>(x_user, pWu, b_in_user, hu_a, NU);
    k_mm<4, true, false, 8><<<gI2, 256, 0, stream>>>(x_item, pWi, b_in_item, hi_a, NI);

    // ---- layer 0 (leaky) ----
    k_sage<4, false, true><<<gI, 256, 0, stream>>>(
        hu_a, hi_a, off_rates, esrc_rates, pRates0, bl_rates, hi_b, NI);
    k_sage<4, false, false><<<gU, 256, 0, stream>>>(
        hi_a, hu_a, off_rated, esrc_rated, pRated0, bSum0, hu_b, NU);
    k_sage<0, true, true><<<gU, 256, 0, stream>>>(
        hu_a, nullptr, off_fol, esrc_fol, pFol0, nullptr, hu_b, NU);

    // ---- layer 1 (no leaky) ----
    k_sage<4, false, false><<<gI, 256, 0, stream>>>(
        hu_b, hi_b, off_rates, esrc_rates, pRates1, bl_rates + 128, hi_a, NI);
    k_sage<4, false, false><<<gU, 256, 0, stream>>>(
        hi_b, hu_b, off_rated, esrc_rated, pRated1, bSum1, hu_a, NU);
    k_sage<0, true, false><<<gU, 256, 0, stream>>>(
        hu_b, nullptr, off_fol, esrc_fol, pFol1, nullptr, hu_a, NU);

    // ---- head (fp32 out) ----
    k_mm<4, false, true, 1><<<gU2, 256, 0, stream>>>(hu_a, pHead, b_out, out, NU);
}

// Round 7
// 988.928 us; speedup vs baseline: 1.0853x; 1.0853x over previous
//
#include <hip/hip_runtime.h>
#include <cstdint>

typedef short short8 __attribute__((ext_vector_type(8)));
typedef float floatx4 __attribute__((ext_vector_type(4)));

constexpr int NU = 200000;   // N_USER
constexpr int NI = 100000;   // N_ITEM
constexpr int NEDGE = 1000000;
constexpr int HD = 128;
constexpr int HH = HD * HD;

// ---- bf16 bit helpers ----
__device__ __forceinline__ float bits2f(short s) {
    return __uint_as_float(((unsigned int)(unsigned short)s) << 16);
}
__device__ __forceinline__ short f2bits(float f) {
    unsigned int u = __float_as_uint(f);
    unsigned int lsb = (u >> 16) & 1u;
    u += 0x7fffu + lsb;   // round-to-nearest-even
    return (short)(u >> 16);
}

// ================= CSR build (r3/r5 proven path) =================
__global__ void k_hist(const int* __restrict__ dst, int* __restrict__ deg, int E) {
    int e = blockIdx.x * 256 + threadIdx.x;
    if (e < E) atomicAdd(&deg[dst[e]], 1);
}

__global__ void k_block_sums(const int* __restrict__ deg, int* __restrict__ bsum, int N) {
    __shared__ int s[1024];
    int t = threadIdx.x;
    int i = blockIdx.x * 1024 + t;
    s[t] = (i < N) ? deg[i] : 0;
    __syncthreads();
    for (int d = 512; d > 0; d >>= 1) {
        if (t < d) s[t] += s[t + d];
        __syncthreads();
    }
    if (t == 0) bsum[blockIdx.x] = s[0];
}

__global__ void k_scan_bsums(const int* __restrict__ bsum, int* __restrict__ boff,
                             int* __restrict__ off, int nb, int N) {
    __shared__ int s[1024];
    int t = threadIdx.x;
    int v = (t < nb) ? bsum[t] : 0;
    s[t] = v;
    __syncthreads();
    for (int d = 1; d < 1024; d <<= 1) {
        int u = (t >= d) ? s[t - d] : 0;
        __syncthreads();
        s[t] += u;
        __syncthreads();
    }
    if (t < nb) boff[t] = s[t] - v;
    if (t == nb - 1) off[N] = s[t];
}

__global__ void k_scan_write(const int* __restrict__ deg, const int* __restrict__ boff,
                             int* __restrict__ off, int N) {
    __shared__ int s[1024];
    int t = threadIdx.x;
    int i = blockIdx.x * 1024 + t;
    int v = (i < N) ? deg[i] : 0;
    s[t] = v;
    __syncthreads();
    for (int d = 1; d < 1024; d <<= 1) {
        int u = (t >= d) ? s[t - d] : 0;
        __syncthreads();
        s[t] += u;
        __syncthreads();
    }
    if (i < N) off[i] = boff[blockIdx.x] + s[t] - v;
}

__global__ void k_fill(const int* __restrict__ src, const int* __restrict__ dst,
                       int* __restrict__ cur, int* __restrict__ esrc, int E) {
    int e = blockIdx.x * 256 + threadIdx.x;
    if (e < E) {
        int pos = atomicAdd(&cur[dst[e]], 1);
        esrc[pos] = src[e];
    }
}

// ================= weight pack (fp32 -> bf16 fragment order) =================
__global__ void k_pack(short* __restrict__ dst, const float* __restrict__ A,
                       const float* __restrict__ B, const float* __restrict__ B2,
                       int KA, int KBr, int NCOL) {
    int l = threadIdx.x;
    int kbt = (KA + KBr) >> 5;
    int nt = blockIdx.x / kbt;
    int kb = blockIdx.x % kbt;
    int col = nt * 16 + (l & 15);
    int k0 = kb * 32 + (l >> 4) * 8;
    short8 o;
#pragma unroll
    for (int j = 0; j < 8; ++j) {
        int k = k0 + j;
        float f;
        if (k < KA) {
            f = A[(size_t)k * NCOL + col];
        } else {
            int k2 = k - KA;
            f = B[(size_t)k2 * NCOL + col];
            if (B2) f += B2[(size_t)k2 * NCOL + col];
        }
        o[j] = f2bits(f);
    }
    *(short8*)(dst + ((size_t)blockIdx.x * 64 + l) * 8) = o;
}

// fold through W_out: P = (Wa (+Wb)) @ Wo  [128x16], packed into slot ntSlot
// of a fragment-order B buffer with KBT=4. Wo is [128,16] row-major.
__global__ void k_foldpack(short* __restrict__ dst, const float* __restrict__ Wa,
                           const float* __restrict__ Wb, const float* __restrict__ Wo,
                           int ntSlot) {
    int l = threadIdx.x;   // 64
    int kb = blockIdx.x;   // 0..3
    int col = l & 15;
    int k0 = kb * 32 + (l >> 4) * 8;
    short8 o;
#pragma unroll
    for (int j = 0; j < 8; ++j) {
        int k = k0 + j;
        float acc = 0.f;
        for (int t = 0; t < 128; ++t) {
            float w = Wa[(size_t)k * 128 + t];
            if (Wb) w += Wb[(size_t)k * 128 + t];
            acc += w * Wo[t * 16 + col];
        }
        o[j] = f2bits(acc);
    }
    *(short8*)(dst + ((size_t)((ntSlot * 4 + kb) * 64 + l)) * 8) = o;
}

// bias16 = (bl1 + bl2) @ Wo + bo
__global__ void k_bfold(float* __restrict__ dst, const float* __restrict__ bl1,
                        const float* __restrict__ bl2, const float* __restrict__ Wo,
                        const float* __restrict__ bo) {
    int c = threadIdx.x;   // 16
    float a = 0.f;
    for (int t = 0; t < 128; ++t) a += (bl1[t] + bl2[t]) * Wo[t * 16 + c];
    dst[c] = a + bo[c];
}

__global__ void k_addbias(float* __restrict__ dst, const float* __restrict__ a,
                          const float* __restrict__ b) {
    int i = threadIdx.x;
    dst[i] = a[i] + b[i];
}

// ================= fused SAGE: gather-mean + MFMA GEMM (layer 0) =================
template <int KB2, bool ACCUM, bool LEAKY>
__global__ __launch_bounds__(256) void k_sage(const short* __restrict__ Xsrc,
                                              const short* __restrict__ A2,
                                              const int* __restrict__ off,
                                              const int* __restrict__ esrc,
                                              const short* __restrict__ Wp,
                                              const float* __restrict__ bias,
                                              short* __restrict__ C, int M) {
    constexpr int KBT = 4 + KB2;
    const int lane = threadIdx.x & 63;
    const int wv = threadIdx.x >> 6;
    const int r0 = blockIdx.x * 64 + wv * 16;

    int ar = r0 + (lane & 15);
    if (ar >= M) ar = M - 1;
    const int ksub = (lane >> 4) * 8;

    float macc[4][8];
#pragma unroll
    for (int kb = 0; kb < 4; ++kb)
#pragma unroll
        for (int i = 0; i < 8; ++i) macc[kb][i] = 0.f;

    const int s = off[ar], e = off[ar + 1];
    int j = s;
    for (; j + 4 <= e; j += 4) {
        const int i0 = esrc[j], i1 = esrc[j + 1], i2 = esrc[j + 2], i3 = esrc[j + 3];
        const short* p0 = Xsrc + (size_t)i0 * HD + ksub;
        const short* p1 = Xsrc + (size_t)i1 * HD + ksub;
        const short* p2 = Xsrc + (size_t)i2 * HD + ksub;
        const short* p3 = Xsrc + (size_t)i3 * HD + ksub;
        short8 v0[4], v1[4], v2[4], v3[4];
#pragma unroll
        for (int kb = 0; kb < 4; ++kb) {
            v0[kb] = *(const short8*)(p0 + kb * 32);
            v1[kb] = *(const short8*)(p1 + kb * 32);
            v2[kb] = *(const short8*)(p2 + kb * 32);
            v3[kb] = *(const short8*)(p3 + kb * 32);
        }
#pragma unroll
        for (int kb = 0; kb < 4; ++kb)
#pragma unroll
            for (int i = 0; i < 8; ++i)
                macc[kb][i] += (bits2f(v0[kb][i]) + bits2f(v1[kb][i]))
                             + (bits2f(v2[kb][i]) + bits2f(v3[kb][i]));
    }
    for (; j < e; ++j) {
        const short* xp = Xsrc + (size_t)esrc[j] * HD + ksub;
#pragma unroll
        for (int kb = 0; kb < 4; ++kb) {
            short8 v = *(const short8*)(xp + kb * 32);
#pragma unroll
            for (int i = 0; i < 8; ++i) macc[kb][i] += bits2f(v[i]);
        }
    }
    const int d = e - s;
    const float inv = 1.f / (float)(d > 0 ? d : 1);

    short8 afrag[KBT];
#pragma unroll
    for (int kb = 0; kb < 4; ++kb) {
        short8 f;
#pragma unroll
        for (int i = 0; i < 8; ++i) f[i] = f2bits(macc[kb][i] * inv);
        afrag[kb] = f;
    }
    if constexpr (KB2 > 0) {
        const short* p = A2 + (size_t)ar * (KB2 * 32) + ksub;
#pragma unroll
        for (int kb = 0; kb < KB2; ++kb) afrag[4 + kb] = *(const short8*)(p + kb * 32);
    }

    floatx4 acc[8];
#pragma unroll
    for (int nt = 0; nt < 8; ++nt) acc[nt] = (floatx4){0.f, 0.f, 0.f, 0.f};

    const short8* wp = (const short8*)Wp + lane;
#pragma unroll
    for (int nt = 0; nt < 8; ++nt) {
#pragma unroll
        for (int kb = 0; kb < KBT; ++kb) {
            short8 b = wp[(nt * KBT + kb) * 64];
            acc[nt] = __builtin_amdgcn_mfma_f32_16x16x32_bf16(afrag[kb], b, acc[nt], 0, 0, 0);
        }
    }

    const int col = lane & 15;
    const int rbase = r0 + (lane >> 4) * 4;
#pragma unroll
    for (int nt = 0; nt < 8; ++nt) {
        float bv = bias ? bias[nt * 16 + col] : 0.f;
#pragma unroll
        for (int r = 0; r < 4; ++r) {
            int row = rbase + r;
            if (row < M) {
                short* cp = C + (size_t)row * HD + nt * 16 + col;
                float v = acc[nt][r] + bv;
                if constexpr (ACCUM) v += bits2f(*cp);
                if constexpr (LEAKY) v = (v >= 0.f) ? v : 0.01f * v;
                *cp = f2bits(v);
            }
        }
    }
}

// ================= plain MFMA GEMM v2: 32 rows/wave =================
template <int KB1, bool AF32, bool OUTF32, int NT>
__global__ __launch_bounds__(256) void k_mm(const void* __restrict__ A1v,
                                            const short* __restrict__ Wp,
                                            const float* __restrict__ bias,
                                            void* __restrict__ Cv, int M) {
    constexpr int KBT = KB1;
    const int lane = threadIdx.x & 63;
    const int wv = threadIdx.x >> 6;
    const int r0 = blockIdx.x * 128 + wv * 32;

    const int ksub = (lane >> 4) * 8;
    short8 afrag[2][KBT];
#pragma unroll
    for (int h = 0; h < 2; ++h) {
        int ar = r0 + h * 16 + (lane & 15);
        if (ar >= M) ar = M - 1;
        if constexpr (AF32) {
            const float* p = (const float*)A1v + (size_t)ar * (KB1 * 32) + ksub;
#pragma unroll
            for (int kb = 0; kb < KB1; ++kb) {
                short8 f;
#pragma unroll
                for (int j = 0; j < 8; ++j) f[j] = f2bits(p[kb * 32 + j]);
                afrag[h][kb] = f;
            }
        } else {
            const short* p = (const short*)A1v + (size_t)ar * (KB1 * 32) + ksub;
#pragma unroll
            for (int kb = 0; kb < KB1; ++kb) afrag[h][kb] = *(const short8*)(p + kb * 32);
        }
    }

    floatx4 acc[2][NT];
#pragma unroll
    for (int h = 0; h < 2; ++h)
#pragma unroll
        for (int nt = 0; nt < NT; ++nt) acc[h][nt] = (floatx4){0.f, 0.f, 0.f, 0.f};

    const short8* wp = (const short8*)Wp + lane;
#pragma unroll
    for (int nt = 0; nt < NT; ++nt) {
#pragma unroll
        for (int kb = 0; kb < KBT; ++kb) {
            short8 b = wp[(nt * KBT + kb) * 64];
            acc[0][nt] = __builtin_amdgcn_mfma_f32_16x16x32_bf16(afrag[0][kb], b, acc[0][nt], 0, 0, 0);
            acc[1][nt] = __builtin_amdgcn_mfma_f32_16x16x32_bf16(afrag[1][kb], b, acc[1][nt], 0, 0, 0);
        }
    }

    const int col = lane & 15;
#pragma unroll
    for (int h = 0; h < 2; ++h) {
        const int rbase = r0 + h * 16 + (lane >> 4) * 4;
#pragma unroll
        for (int nt = 0; nt < NT; ++nt) {
            float bv = bias ? bias[nt * 16 + col] : 0.f;
#pragma unroll
            for (int r = 0; r < 4; ++r) {
                int row = rbase + r;
                if (row < M) {
                    float v = acc[h][nt][r] + bv;
                    if constexpr (OUTF32) {
                        ((float*)Cv)[(size_t)row * (NT * 16) + nt * 16 + col] = v;
                    } else {
                        ((short*)Cv)[(size_t)row * (NT * 16) + nt * 16 + col] = f2bits(v);
                    }
                }
            }
        }
    }
}

// ================= final output: dual 16-dim gather-mean + residual + bias =================
// out[u][:] = mean_fol(YZ[nbr][0:16]) + mean_rated(YI[nbr][:]) + YZ[u][16:32] + bias16
// 2 threads per node (8 cols each, 16B bf16 loads); edge loops unrolled x4.
__global__ __launch_bounds__(256) void k_out(const short* __restrict__ YZ,
                                             const short* __restrict__ YI,
                                             const int* __restrict__ off_f,
                                             const int* __restrict__ esrc_f,
                                             const int* __restrict__ off_r,
                                             const int* __restrict__ esrc_r,
                                             const float* __restrict__ bias16,
                                             float* __restrict__ out, int N) {
    int t = threadIdx.x;
    int node = blockIdx.x * 128 + (t >> 1);
    int half = t & 1;
    if (node >= N) return;
    const int c0 = half * 8;

    float a[8] = {0.f, 0.f, 0.f, 0.f, 0.f, 0.f, 0.f, 0.f};
    {
        const int s = off_f[node], e = off_f[node + 1];
        int j = s;
        for (; j + 4 <= e; j += 4) {
            short8 v0 = *(const short8*)(YZ + (size_t)esrc_f[j] * 32 + c0);
            short8 v1 = *(const short8*)(YZ + (size_t)esrc_f[j + 1] * 32 + c0);
            short8 v2 = *(const short8*)(YZ + (size_t)esrc_f[j + 2] * 32 + c0);
            short8 v3 = *(const short8*)(YZ + (size_t)esrc_f[j + 3] * 32 + c0);
#pragma unroll
            for (int i = 0; i < 8; ++i)
                a[i] += (bits2f(v0[i]) + bits2f(v1[i])) + (bits2f(v2[i]) + bits2f(v3[i]));
        }
        for (; j < e; ++j) {
            short8 v = *(const short8*)(YZ + (size_t)esrc_f[j] * 32 + c0);
#pragma unroll
            for (int i = 0; i < 8; ++i) a[i] += bits2f(v[i]);
        }
        int d = e - s;
        float inv = 1.f / (float)(d > 0 ? d : 1);
#pragma unroll
        for (int i = 0; i < 8; ++i) a[i] *= inv;
    }
    {
        float b[8] = {0.f, 0.f, 0.f, 0.f, 0.f, 0.f, 0.f, 0.f};
        const int s = off_r[node], e = off_r[node + 1];
        int j = s;
        for (; j + 4 <= e; j += 4) {
            short8 v0 = *(const short8*)(YI + (size_t)esrc_r[j] * 16 + c0);
            short8 v1 = *(const short8*)(YI + (size_t)esrc_r[j + 1] * 16 + c0);
            short8 v2 = *(const short8*)(YI + (size_t)esrc_r[j + 2] * 16 + c0);
            short8 v3 = *(const short8*)(YI + (size_t)esrc_r[j + 3] * 16 + c0);
#pragma unroll
            for (int i = 0; i < 8; ++i)
                b[i] += (bits2f(v0[i]) + bits2f(v1[i])) + (bits2f(v2[i]) + bits2f(v3[i]));
        }
        for (; j < e; ++j) {
            short8 v = *(const short8*)(YI + (size_t)esrc_r[j] * 16 + c0);
#pragma unroll
            for (int i = 0; i < 8; ++i) b[i] += bits2f(v[i]);
        }
        int d = e - s;
        float inv = 1.f / (float)(d > 0 ? d : 1);
#pragma unroll
        for (int i = 0; i < 8; ++i) a[i] += b[i] * inv;
    }
    // residual (z-part) + bias
    short8 z = *(const short8*)(YZ + (size_t)node * 32 + 16 + c0);
#pragma unroll
    for (int i = 0; i < 8; ++i)
        out[(size_t)node * 16 + c0 + i] = a[i] + bits2f(z[i]) + bias16[c0 + i];
}

// ================= launch =================
extern "C" void kernel_launch(void* const* d_in, const int* in_sizes, int n_in,
                              void* d_out, int out_size, void* d_ws, size_t ws_size,
                              hipStream_t stream) {
    const float* x_user    = (const float*)d_in[0];
    const float* x_item    = (const float*)d_in[1];
    const int* src_rates   = (const int*)d_in[2];
    const int* dst_rates   = (const int*)d_in[3];
    const int* src_rated   = (const int*)d_in[4];
    const int* dst_rated   = (const int*)d_in[5];
    const int* src_fol     = (const int*)d_in[6];
    const int* dst_fol     = (const int*)d_in[7];
    const float* W_in_user = (const float*)d_in[8];
    const float* b_in_user = (const float*)d_in[9];
    const float* W_in_item = (const float*)d_in[10];
    const float* b_in_item = (const float*)d_in[11];
    const float* Wl_rates  = (const float*)d_in[12];
    const float* bl_rates  = (const float*)d_in[13];
    const float* Wr_rates  = (const float*)d_in[14];
    const float* Wl_rated  = (const float*)d_in[15];
    const float* bl_rated  = (const float*)d_in[16];
    const float* Wr_rated  = (const float*)d_in[17];
    const float* Wl_fol    = (const float*)d_in[18];
    const float* bl_fol    = (const float*)d_in[19];
    const float* Wr_fol    = (const float*)d_in[20];
    const float* W_out     = (const float*)d_in[21];
    const float* b_out     = (const float*)d_in[22];
    float* out = (float*)d_out;

    char* w = (char*)d_ws;
    size_t used = 0;
    auto alloc = [&](size_t bytes) -> void* {
        void* p = w + used;
        used += (bytes + 255) & ~(size_t)255;
        return p;
    };
    short* hu_a = (short*)alloc((size_t)NU * HD * 2);
    short* hu_b = (short*)alloc((size_t)NU * HD * 2);
    short* hi_a = (short*)alloc((size_t)NI * HD * 2);
    short* hi_b = (short*)alloc((size_t)NI * HD * 2);
    short* YZ   = (short*)alloc((size_t)NU * 32 * 2);   // [yu_fol' | zu]
    short* YI   = (short*)alloc((size_t)NI * 16 * 2);   // yi_rated'

    int* deg_rates  = (int*)alloc((size_t)NI * 4);
    int* off_rates  = (int*)alloc((size_t)(NI + 1) * 4);
    int* cur_rates  = (int*)alloc((size_t)NI * 4);
    int* esrc_rates = (int*)alloc((size_t)NEDGE * 4);
    int* deg_rated  = (int*)alloc((size_t)NU * 4);
    int* off_rated  = (int*)alloc((size_t)(NU + 1) * 4);
    int* cur_rated  = (int*)alloc((size_t)NU * 4);
    int* esrc_rated = (int*)alloc((size_t)NEDGE * 4);
    int* deg_fol    = (int*)alloc((size_t)NU * 4);
    int* off_fol    = (int*)alloc((size_t)(NU + 1) * 4);
    int* cur_fol    = (int*)alloc((size_t)NU * 4);
    int* esrc_fol   = (int*)alloc((size_t)NEDGE * 4);
    int* bsum = (int*)alloc(1024 * 4);
    int* boff = (int*)alloc(1024 * 4);

    short* pWu      = (short*)alloc(8 * 2 * 64 * 8 * 2);
    short* pWi      = (short*)alloc(8 * 4 * 64 * 8 * 2);
    short* pRates0  = (short*)alloc(8 * 8 * 64 * 8 * 2);
    short* pRated0  = (short*)alloc(8 * 8 * 64 * 8 * 2);
    short* pFol0    = (short*)alloc(8 * 4 * 64 * 8 * 2);
    short* pFoldA   = (short*)alloc(2 * 4 * 64 * 8 * 2);  // NT=2, KBT=4
    short* pFoldB   = (short*)alloc(1 * 4 * 64 * 8 * 2);  // NT=1, KBT=4
    float* bSum0    = (float*)alloc(128 * 4);
    float* bias16   = (float*)alloc(16 * 4);
    if (used > ws_size) return;   // diagnostic signature: output stays zero

    auto build_csr = [&](const int* dstA, const int* srcA, int N, int* deg, int* off,
                         int* cur, int* esrc) {
        hipMemsetAsync(deg, 0, (size_t)N * 4, stream);
        k_hist<<<(NEDGE + 255) / 256, 256, 0, stream>>>(dstA, deg, NEDGE);
        int nb = (N + 1023) / 1024;
        k_block_sums<<<nb, 1024, 0, stream>>>(deg, bsum, N);
        k_scan_bsums<<<1, 1024, 0, stream>>>(bsum, boff, off, nb, N);
        k_scan_write<<<nb, 1024, 0, stream>>>(deg, boff, off, N);
        hipMemcpyAsync(cur, off, (size_t)N * 4, hipMemcpyDeviceToDevice, stream);
        k_fill<<<(NEDGE + 255) / 256, 256, 0, stream>>>(srcA, dstA, cur, esrc, NEDGE);
    };

    build_csr(dst_rates, src_rates, NI, deg_rates, off_rates, cur_rates, esrc_rates);
    build_csr(dst_rated, src_rated, NU, deg_rated, off_rated, cur_rated, esrc_rated);
    build_csr(dst_fol,   src_fol,   NU, deg_fol,   off_fol,   cur_fol,   esrc_fol);

    // ---- weight packing ----
    k_pack<<<16, 64, 0, stream>>>(pWu, W_in_user, nullptr, nullptr, 64, 0, 128);
    k_pack<<<32, 64, 0, stream>>>(pWi, W_in_item, nullptr, nullptr, 128, 0, 128);
    k_pack<<<64, 64, 0, stream>>>(pRates0, Wl_rates, Wr_rates, nullptr,     128, 128, 128);
    k_pack<<<64, 64, 0, stream>>>(pRated0, Wl_rated, Wr_rated, Wr_fol,      128, 128, 128);
    k_pack<<<32, 64, 0, stream>>>(pFol0,   Wl_fol,   nullptr,  nullptr,     128, 0, 128);
    k_addbias<<<1, 128, 0, stream>>>(bSum0, bl_rated, bl_fol);
    // layer-1 weights folded through W_out
    k_foldpack<<<4, 64, 0, stream>>>(pFoldA, Wl_fol + HH,   nullptr,      W_out, 0);
    k_foldpack<<<4, 64, 0, stream>>>(pFoldA, Wr_rated + HH, Wr_fol + HH,  W_out, 1);
    k_foldpack<<<4, 64, 0, stream>>>(pFoldB, Wl_rated + HH, nullptr,      W_out, 0);
    k_bfold<<<1, 16, 0, stream>>>(bias16, bl_rated + 128, bl_fol + 128, W_out, b_out);

    const int gU2 = (NU + 127) / 128;
    const int gI2 = (NI + 127) / 128;
    const int gU  = (NU + 63) / 64;
    const int gI  = (NI + 63) / 64;

    // ---- input projections (fp32 A) ----
    k_mm<2, true, false, 8><<<gU2, 256, 0, stream>>>(x_user, pWu, b_in_user, hu_a, NU);
    k_mm<4, true, false, 8><<<gI2, 256, 0, stream>>>(x_item, pWi, b_in_item, hi_a, NI);

    // ---- layer 0 (leaky) ----
    k_sage<4, false, true><<<gI, 256, 0, stream>>>(
        hu_a, hi_a, off_rates, esrc_rates, pRates0, bl_rates, hi_b, NI);
    k_sage<4, false, false><<<gU, 256, 0, stream>>>(
        hi_a, hu_a, off_rated, esrc_rated, pRated0, bSum0, hu_b, NU);
    k_sage<0, true, true><<<gU, 256, 0, stream>>>(
        hu_a, nullptr, off_fol, esrc_fol, pFol0, nullptr, hu_b, NU);

    // ---- layer 1: dense 16-dim projections (item SAGE is dead code; removed) ----
    k_mm<4, false, false, 2><<<gU2, 256, 0, stream>>>(hu_b, pFoldA, nullptr, YZ, NU);
    k_mm<4, false, false, 1><<<gI2, 256, 0, stream>>>(hi_b, pFoldB, nullptr, YI, NI);

    // ---- final: dual 16-dim gather-mean + residual + bias -> fp32 out ----
    k_out<<<(NU + 127) / 128, 256, 0, stream>>>(
        YZ, YI, off_fol, esrc_fol, off_rated, esrc_rated, bias16, out, NU);
}

// Round 8
// 977.494 us; speedup vs baseline: 1.0980x; 1.0117x over previous
//
#include <hip/hip_runtime.h>
#include <cstdint>

typedef short short8 __attribute__((ext_vector_type(8)));
typedef float floatx4 __attribute__((ext_vector_type(4)));

constexpr int NU = 200000;   // N_USER
constexpr int NI = 100000;   // N_ITEM
constexpr int NEDGE = 1000000;
constexpr int HD = 128;
constexpr int HH = HD * HD;

// ---- bf16 bit helpers ----
__device__ __forceinline__ float bits2f(short s) {
    return __uint_as_float(((unsigned int)(unsigned short)s) << 16);
}
__device__ __forceinline__ short f2bits(float f) {
    unsigned int u = __float_as_uint(f);
    unsigned int lsb = (u >> 16) & 1u;
    u += 0x7fffu + lsb;   // round-to-nearest-even
    return (short)(u >> 16);
}

// ================= CSR build =================
__global__ void k_hist(const int* __restrict__ dst, int* __restrict__ deg, int E) {
    int e = blockIdx.x * 256 + threadIdx.x;
    if (e < E) atomicAdd(&deg[dst[e]], 1);
}

__global__ void k_block_sums(const int* __restrict__ deg, int* __restrict__ bsum, int N) {
    __shared__ int s[1024];
    int t = threadIdx.x;
    int i = blockIdx.x * 1024 + t;
    s[t] = (i < N) ? deg[i] : 0;
    __syncthreads();
    for (int d = 512; d > 0; d >>= 1) {
        if (t < d) s[t] += s[t + d];
        __syncthreads();
    }
    if (t == 0) bsum[blockIdx.x] = s[0];
}

__global__ void k_scan_bsums(const int* __restrict__ bsum, int* __restrict__ boff,
                             int* __restrict__ off, int nb, int N) {
    __shared__ int s[1024];
    int t = threadIdx.x;
    int v = (t < nb) ? bsum[t] : 0;
    s[t] = v;
    __syncthreads();
    for (int d = 1; d < 1024; d <<= 1) {
        int u = (t >= d) ? s[t - d] : 0;
        __syncthreads();
        s[t] += u;
        __syncthreads();
    }
    if (t < nb) boff[t] = s[t] - v;
    if (t == nb - 1) off[N] = s[t];
}

// writes off AND cur (cur seeded = off; drops the d2d copy)
__global__ void k_scan_write(const int* __restrict__ deg, const int* __restrict__ boff,
                             int* __restrict__ off, int* __restrict__ cur, int N) {
    __shared__ int s[1024];
    int t = threadIdx.x;
    int i = blockIdx.x * 1024 + t;
    int v = (i < N) ? deg[i] : 0;
    s[t] = v;
    __syncthreads();
    for (int d = 1; d < 1024; d <<= 1) {
        int u = (t >= d) ? s[t - d] : 0;
        __syncthreads();
        s[t] += u;
        __syncthreads();
    }
    if (i < N) {
        int o = boff[blockIdx.x] + s[t] - v;
        off[i] = o;
        cur[i] = o;
    }
}

__global__ void k_fill(const int* __restrict__ src, const int* __restrict__ dst,
                       int* __restrict__ cur, int* __restrict__ esrc, int E) {
    int e = blockIdx.x * 256 + threadIdx.x;
    if (e < E) {
        int sv = src[e];
        int pos = atomicAdd(&cur[dst[e]], 1);
        esrc[pos] = sv;
    }
}

// ================= weight pack (fp32 -> bf16 fragment order) =================
__global__ void k_pack(short* __restrict__ dst, const float* __restrict__ A,
                       const float* __restrict__ B, const float* __restrict__ B2,
                       int KA, int KBr, int NCOL) {
    int l = threadIdx.x;
    int kbt = (KA + KBr) >> 5;
    int nt = blockIdx.x / kbt;
    int kb = blockIdx.x % kbt;
    int col = nt * 16 + (l & 15);
    int k0 = kb * 32 + (l >> 4) * 8;
    short8 o;
#pragma unroll
    for (int j = 0; j < 8; ++j) {
        int k = k0 + j;
        float f;
        if (k < KA) {
            f = A[(size_t)k * NCOL + col];
        } else {
            int k2 = k - KA;
            f = B[(size_t)k2 * NCOL + col];
            if (B2) f += B2[(size_t)k2 * NCOL + col];
        }
        o[j] = f2bits(f);
    }
    *(short8*)(dst + ((size_t)blockIdx.x * 64 + l) * 8) = o;
}

// 3-section pack: W2 = [A(128) ; B(128) ; C1+C2(128)], KBT=12, NCOL=128
__global__ void k_pack3(short* __restrict__ dst, const float* __restrict__ A,
                        const float* __restrict__ B, const float* __restrict__ C1,
                        const float* __restrict__ C2) {
    int l = threadIdx.x;
    constexpr int kbt = 12;
    int nt = blockIdx.x / kbt;
    int kb = blockIdx.x % kbt;
    int col = nt * 16 + (l & 15);
    int k0 = kb * 32 + (l >> 4) * 8;
    short8 o;
#pragma unroll
    for (int j = 0; j < 8; ++j) {
        int k = k0 + j;
        float f;
        if (k < 128) f = A[(size_t)k * 128 + col];
        else if (k < 256) f = B[(size_t)(k - 128) * 128 + col];
        else f = C1[(size_t)(k - 256) * 128 + col] + C2[(size_t)(k - 256) * 128 + col];
        o[j] = f2bits(f);
    }
    *(short8*)(dst + ((size_t)blockIdx.x * 64 + l) * 8) = o;
}

// fold through W_out: P = (Wa (+Wb)) @ Wo  [128x16] into slot ntSlot (KBT=4)
__global__ void k_foldpack(short* __restrict__ dst, const float* __restrict__ Wa,
                           const float* __restrict__ Wb, const float* __restrict__ Wo,
                           int ntSlot) {
    int l = threadIdx.x;
    int kb = blockIdx.x;
    int col = l & 15;
    int k0 = kb * 32 + (l >> 4) * 8;
    short8 o;
#pragma unroll
    for (int j = 0; j < 8; ++j) {
        int k = k0 + j;
        float acc = 0.f;
        for (int t = 0; t < 128; ++t) {
            float w = Wa[(size_t)k * 128 + t];
            if (Wb) w += Wb[(size_t)k * 128 + t];
            acc += w * Wo[t * 16 + col];
        }
        o[j] = f2bits(acc);
    }
    *(short8*)(dst + ((size_t)((ntSlot * 4 + kb) * 64 + l)) * 8) = o;
}

__global__ void k_bfold(float* __restrict__ dst, const float* __restrict__ bl1,
                        const float* __restrict__ bl2, const float* __restrict__ Wo,
                        const float* __restrict__ bo) {
    int c = threadIdx.x;
    float a = 0.f;
    for (int t = 0; t < 128; ++t) a += (bl1[t] + bl2[t]) * Wo[t * 16 + c];
    dst[c] = a + bo[c];
}

__global__ void k_addbias(float* __restrict__ dst, const float* __restrict__ a,
                          const float* __restrict__ b) {
    int i = threadIdx.x;
    dst[i] = a[i] + b[i];
}

// ---- shared gather-mean helper: accumulates mean into macc[4][8] ----
__device__ __forceinline__ void gather_mean(const short* __restrict__ Xsrc,
                                            const int* __restrict__ off,
                                            const int* __restrict__ esrc,
                                            int ar, int ksub, float macc[4][8]) {
#pragma unroll
    for (int kb = 0; kb < 4; ++kb)
#pragma unroll
        for (int i = 0; i < 8; ++i) macc[kb][i] = 0.f;

    const int s = off[ar], e = off[ar + 1];
    int j = s;
    int n0 = 0, n1 = 0, n2 = 0, n3 = 0;
    if (j + 4 <= e) { n0 = esrc[j]; n1 = esrc[j + 1]; n2 = esrc[j + 2]; n3 = esrc[j + 3]; }
    for (; j + 4 <= e; ) {
        const int i0 = n0, i1 = n1, i2 = n2, i3 = n3;
        int jn = j + 4;
        if (jn + 4 <= e) {   // prefetch next batch's indices early
            n0 = esrc[jn]; n1 = esrc[jn + 1]; n2 = esrc[jn + 2]; n3 = esrc[jn + 3];
        }
        const short* p0 = Xsrc + (size_t)i0 * HD + ksub;
        const short* p1 = Xsrc + (size_t)i1 * HD + ksub;
        const short* p2 = Xsrc + (size_t)i2 * HD + ksub;
        const short* p3 = Xsrc + (size_t)i3 * HD + ksub;
        short8 v0[4], v1[4], v2[4], v3[4];
#pragma unroll
        for (int kb = 0; kb < 4; ++kb) {
            v0[kb] = *(const short8*)(p0 + kb * 32);
            v1[kb] = *(const short8*)(p1 + kb * 32);
            v2[kb] = *(const short8*)(p2 + kb * 32);
            v3[kb] = *(const short8*)(p3 + kb * 32);
        }
#pragma unroll
        for (int kb = 0; kb < 4; ++kb)
#pragma unroll
            for (int i = 0; i < 8; ++i)
                macc[kb][i] += (bits2f(v0[kb][i]) + bits2f(v1[kb][i]))
                             + (bits2f(v2[kb][i]) + bits2f(v3[kb][i]));
        j = jn;
    }
    for (; j < e; ++j) {
        const short* xp = Xsrc + (size_t)esrc[j] * HD + ksub;
#pragma unroll
        for (int kb = 0; kb < 4; ++kb) {
            short8 v = *(const short8*)(xp + kb * 32);
#pragma unroll
            for (int i = 0; i < 8; ++i) macc[kb][i] += bits2f(v[i]);
        }
    }
    const int d = e - s;
    const float inv = 1.f / (float)(d > 0 ? d : 1);
#pragma unroll
    for (int kb = 0; kb < 4; ++kb)
#pragma unroll
        for (int i = 0; i < 8; ++i) macc[kb][i] *= inv;
}

// ================= fused SAGE (single gather): layer-0 item update =================
template <int KB2, bool LEAKY>
__global__ __launch_bounds__(256) void k_sage(const short* __restrict__ Xsrc,
                                              const short* __restrict__ A2,
                                              const int* __restrict__ off,
                                              const int* __restrict__ esrc,
                                              const short* __restrict__ Wp,
                                              const float* __restrict__ bias,
                                              short* __restrict__ C, int M) {
    constexpr int KBT = 4 + KB2;
    const int lane = threadIdx.x & 63;
    const int wv = threadIdx.x >> 6;
    const int r0 = blockIdx.x * 64 + wv * 16;

    int ar = r0 + (lane & 15);
    if (ar >= M) ar = M - 1;
    const int ksub = (lane >> 4) * 8;

    float macc[4][8];
    gather_mean(Xsrc, off, esrc, ar, ksub, macc);

    short8 afrag[KBT];
#pragma unroll
    for (int kb = 0; kb < 4; ++kb) {
        short8 f;
#pragma unroll
        for (int i = 0; i < 8; ++i) f[i] = f2bits(macc[kb][i]);
        afrag[kb] = f;
    }
    if constexpr (KB2 > 0) {
        const short* p = A2 + (size_t)ar * (KB2 * 32) + ksub;
#pragma unroll
        for (int kb = 0; kb < KB2; ++kb) afrag[4 + kb] = *(const short8*)(p + kb * 32);
    }

    floatx4 acc[8];
#pragma unroll
    for (int nt = 0; nt < 8; ++nt) acc[nt] = (floatx4){0.f, 0.f, 0.f, 0.f};

    const short8* wp = (const short8*)Wp + lane;
#pragma unroll
    for (int nt = 0; nt < 8; ++nt) {
#pragma unroll
        for (int kb = 0; kb < KBT; ++kb) {
            short8 b = wp[(nt * KBT + kb) * 64];
            acc[nt] = __builtin_amdgcn_mfma_f32_16x16x32_bf16(afrag[kb], b, acc[nt], 0, 0, 0);
        }
    }

    const int col = lane & 15;
    const int rbase = r0 + (lane >> 4) * 4;
#pragma unroll
    for (int nt = 0; nt < 8; ++nt) {
        float bv = bias ? bias[nt * 16 + col] : 0.f;
#pragma unroll
        for (int r = 0; r < 4; ++r) {
            int row = rbase + r;
            if (row < M) {
                float v = acc[nt][r] + bv;
                if constexpr (LEAKY) v = (v >= 0.f) ? v : 0.01f * v;
                C[(size_t)row * HD + nt * 16 + col] = f2bits(v);
            }
        }
    }
}

// ================= fused dual-gather SAGE: layer-0 user update =================
// C = mean_rated(Hi)@Wl_rated + mean_fol(Hu)@Wl_fol + Hu@(Wr_rated+Wr_fol) + bias
// B packed [Wl_rated; Wl_fol; Wr_sum], KBT=12. One write, no ACCUM round-trip.
template <bool LEAKY>
__global__ __launch_bounds__(256) void k_sage2(const short* __restrict__ Hi,
                                               const short* __restrict__ Hu,
                                               const int* __restrict__ off_r,
                                               const int* __restrict__ esrc_r,
                                               const int* __restrict__ off_f,
                                               const int* __restrict__ esrc_f,
                                               const short* __restrict__ Wp,
                                               const float* __restrict__ bias,
                                               short* __restrict__ C, int M) {
    constexpr int KBT = 12;
    const int lane = threadIdx.x & 63;
    const int wv = threadIdx.x >> 6;
    const int r0 = blockIdx.x * 64 + wv * 16;

    int ar = r0 + (lane & 15);
    if (ar >= M) ar = M - 1;
    const int ksub = (lane >> 4) * 8;

    short8 afrag[KBT];
    {
        float macc[4][8];
        gather_mean(Hi, off_r, esrc_r, ar, ksub, macc);
#pragma unroll
        for (int kb = 0; kb < 4; ++kb) {
            short8 f;
#pragma unroll
            for (int i = 0; i < 8; ++i) f[i] = f2bits(macc[kb][i]);
            afrag[kb] = f;
        }
        gather_mean(Hu, off_f, esrc_f, ar, ksub, macc);
#pragma unroll
        for (int kb = 0; kb < 4; ++kb) {
            short8 f;
#pragma unroll
            for (int i = 0; i < 8; ++i) f[i] = f2bits(macc[kb][i]);
            afrag[4 + kb] = f;
        }
    }
    {
        const short* p = Hu + (size_t)ar * HD + ksub;
#pragma unroll
        for (int kb = 0; kb < 4; ++kb) afrag[8 + kb] = *(const short8*)(p + kb * 32);
    }

    floatx4 acc[8];
#pragma unroll
    for (int nt = 0; nt < 8; ++nt) acc[nt] = (floatx4){0.f, 0.f, 0.f, 0.f};

    const short8* wp = (const short8*)Wp + lane;
#pragma unroll
    for (int nt = 0; nt < 8; ++nt) {
#pragma unroll
        for (int kb = 0; kb < KBT; ++kb) {
            short8 b = wp[(nt * KBT + kb) * 64];
            acc[nt] = __builtin_amdgcn_mfma_f32_16x16x32_bf16(afrag[kb], b, acc[nt], 0, 0, 0);
        }
    }

    const int col = lane & 15;
    const int rbase = r0 + (lane >> 4) * 4;
#pragma unroll
    for (int nt = 0; nt < 8; ++nt) {
        float bv = bias[nt * 16 + col];
#pragma unroll
        for (int r = 0; r < 4; ++r) {
            int row = rbase + r;
            if (row < M) {
                float v = acc[nt][r] + bv;
                if constexpr (LEAKY) v = (v >= 0.f) ? v : 0.01f * v;
                C[(size_t)row * HD + nt * 16 + col] = f2bits(v);
            }
        }
    }
}

// ================= plain MFMA GEMM v2: 32 rows/wave =================
template <int KB1, bool AF32, bool OUTF32, int NT>
__global__ __launch_bounds__(256) void k_mm(const void* __restrict__ A1v,
                                            const short* __restrict__ Wp,
                                            const float* __restrict__ bias,
                                            void* __restrict__ Cv, int M) {
    constexpr int KBT = KB1;
    const int lane = threadIdx.x & 63;
    const int wv = threadIdx.x >> 6;
    const int r0 = blockIdx.x * 128 + wv * 32;

    const int ksub = (lane >> 4) * 8;
    short8 afrag[2][KBT];
#pragma unroll
    for (int h = 0; h < 2; ++h) {
        int ar = r0 + h * 16 + (lane & 15);
        if (ar >= M) ar = M - 1;
        if constexpr (AF32) {
            const float* p = (const float*)A1v + (size_t)ar * (KB1 * 32) + ksub;
#pragma unroll
            for (int kb = 0; kb < KB1; ++kb) {
                short8 f;
#pragma unroll
                for (int j = 0; j < 8; ++j) f[j] = f2bits(p[kb * 32 + j]);
                afrag[h][kb] = f;
            }
        } else {
            const short* p = (const short*)A1v + (size_t)ar * (KB1 * 32) + ksub;
#pragma unroll
            for (int kb = 0; kb < KB1; ++kb) afrag[h][kb] = *(const short8*)(p + kb * 32);
        }
    }

    floatx4 acc[2][NT];
#pragma unroll
    for (int h = 0; h < 2; ++h)
#pragma unroll
        for (int nt = 0; nt < NT; ++nt) acc[h][nt] = (floatx4){0.f, 0.f, 0.f, 0.f};

    const short8* wp = (const short8*)Wp + lane;
#pragma unroll
    for (int nt = 0; nt < NT; ++nt) {
#pragma unroll
        for (int kb = 0; kb < KBT; ++kb) {
            short8 b = wp[(nt * KBT + kb) * 64];
            acc[0][nt] = __builtin_amdgcn_mfma_f32_16x16x32_bf16(afrag[0][kb], b, acc[0][nt], 0, 0, 0);
            acc[1][nt] = __builtin_amdgcn_mfma_f32_16x16x32_bf16(afrag[1][kb], b, acc[1][nt], 0, 0, 0);
        }
    }

    const int col = lane & 15;
#pragma unroll
    for (int h = 0; h < 2; ++h) {
        const int rbase = r0 + h * 16 + (lane >> 4) * 4;
#pragma unroll
        for (int nt = 0; nt < NT; ++nt) {
            float bv = bias ? bias[nt * 16 + col] : 0.f;
#pragma unroll
            for (int r = 0; r < 4; ++r) {
                int row = rbase + r;
                if (row < M) {
                    float v = acc[h][nt][r] + bv;
                    if constexpr (OUTF32) {
                        ((float*)Cv)[(size_t)row * (NT * 16) + nt * 16 + col] = v;
                    } else {
                        ((short*)Cv)[(size_t)row * (NT * 16) + nt * 16 + col] = f2bits(v);
                    }
                }
            }
        }
    }
}

// ================= final output: dual 16-dim gather-mean + residual + bias =================
__global__ __launch_bounds__(256) void k_out(const short* __restrict__ YZ,
                                             const short* __restrict__ YI,
                                             const int* __restrict__ off_f,
                                             const int* __restrict__ esrc_f,
                                             const int* __restrict__ off_r,
                                             const int* __restrict__ esrc_r,
                                             const float* __restrict__ bias16,
                                             float* __restrict__ out, int N) {
    int t = threadIdx.x;
    int node = blockIdx.x * 128 + (t >> 1);
    int half = t & 1;
    if (node >= N) return;
    const int c0 = half * 8;

    float a[8] = {0.f, 0.f, 0.f, 0.f, 0.f, 0.f, 0.f, 0.f};
    {
        const int s = off_f[node], e = off_f[node + 1];
        int j = s;
        for (; j + 4 <= e; j += 4) {
            short8 v0 = *(const short8*)(YZ + (size_t)esrc_f[j] * 32 + c0);
            short8 v1 = *(const short8*)(YZ + (size_t)esrc_f[j + 1] * 32 + c0);
            short8 v2 = *(const short8*)(YZ + (size_t)esrc_f[j + 2] * 32 + c0);
            short8 v3 = *(const short8*)(YZ + (size_t)esrc_f[j + 3] * 32 + c0);
#pragma unroll
            for (int i = 0; i < 8; ++i)
                a[i] += (bits2f(v0[i]) + bits2f(v1[i])) + (bits2f(v2[i]) + bits2f(v3[i]));
        }
        for (; j < e; ++j) {
            short8 v = *(const short8*)(YZ + (size_t)esrc_f[j] * 32 + c0);
#pragma unroll
            for (int i = 0; i < 8; ++i) a[i] += bits2f(v[i]);
        }
        int d = e - s;
        float inv = 1.f / (float)(d > 0 ? d : 1);
#pragma unroll
        for (int i = 0; i < 8; ++i) a[i] *= inv;
    }
    {
        float b[8] = {0.f, 0.f, 0.f, 0.f, 0.f, 0.f, 0.f, 0.f};
        const int s = off_r[node], e = off_r[node + 1];
        int j = s;
        for (; j + 4 <= e; j += 4) {
            short8 v0 = *(const short8*)(YI + (size_t)esrc_r[j] * 16 + c0);
            short8 v1 = *(const short8*)(YI + (size_t)esrc_r[j + 1] * 16 + c0);
            short8 v2 = *(const short8*)(YI + (size_t)esrc_r[j + 2] * 16 + c0);
            short8 v3 = *(const short8*)(YI + (size_t)esrc_r[j + 3] * 16 + c0);
#pragma unroll
            for (int i = 0; i < 8; ++i)
                b[i] += (bits2f(v0[i]) + bits2f(v1[i])) + (bits2f(v2[i]) + bits2f(v3[i]));
        }
        for (; j < e; ++j) {
            short8 v = *(const short8*)(YI + (size_t)esrc_r[j] * 16 + c0);
#pragma unroll
            for (int i = 0; i < 8; ++i) b[i] += bits2f(v[i]);
        }
        int d = e - s;
        float inv = 1.f / (float)(d > 0 ? d : 1);
#pragma unroll
        for (int i = 0; i < 8; ++i) a[i] += b[i] * inv;
    }
    short8 z = *(const short8*)(YZ + (size_t)node * 32 + 16 + c0);
#pragma unroll
    for (int i = 0; i < 8; ++i)
        out[(size_t)node * 16 + c0 + i] = a[i] + bits2f(z[i]) + bias16[c0 + i];
}

// ================= launch =================
extern "C" void kernel_launch(void* const* d_in, const int* in_sizes, int n_in,
                              void* d_out, int out_size, void* d_ws, size_t ws_size,
                              hipStream_t stream) {
    const float* x_user    = (const float*)d_in[0];
    const float* x_item    = (const float*)d_in[1];
    const int* src_rates   = (const int*)d_in[2];
    const int* dst_rates   = (const int*)d_in[3];
    const int* src_rated   = (const int*)d_in[4];
    const int* dst_rated   = (const int*)d_in[5];
    const int* src_fol     = (const int*)d_in[6];
    const int* dst_fol     = (const int*)d_in[7];
    const float* W_in_user = (const float*)d_in[8];
    const float* b_in_user = (const float*)d_in[9];
    const float* W_in_item = (const float*)d_in[10];
    const float* b_in_item = (const float*)d_in[11];
    const float* Wl_rates  = (const float*)d_in[12];
    const float* bl_rates  = (const float*)d_in[13];
    const float* Wr_rates  = (const float*)d_in[14];
    const float* Wl_rated  = (const float*)d_in[15];
    const float* bl_rated  = (const float*)d_in[16];
    const float* Wr_rated  = (const float*)d_in[17];
    const float* Wl_fol    = (const float*)d_in[18];
    const float* bl_fol    = (const float*)d_in[19];
    const float* Wr_fol    = (const float*)d_in[20];
    const float* W_out     = (const float*)d_in[21];
    const float* b_out     = (const float*)d_in[22];
    float* out = (float*)d_out;

    char* w = (char*)d_ws;
    size_t used = 0;
    auto alloc = [&](size_t bytes) -> void* {
        void* p = w + used;
        used += (bytes + 255) & ~(size_t)255;
        return p;
    };
    short* hu_a = (short*)alloc((size_t)NU * HD * 2);
    short* hu_b = (short*)alloc((size_t)NU * HD * 2);
    short* hi_a = (short*)alloc((size_t)NI * HD * 2);
    short* hi_b = (short*)alloc((size_t)NI * HD * 2);
    short* YZ   = (short*)alloc((size_t)NU * 32 * 2);
    short* YI   = (short*)alloc((size_t)NI * 16 * 2);

    int* deg_rates  = (int*)alloc((size_t)NI * 4);
    int* off_rates  = (int*)alloc((size_t)(NI + 1) * 4);
    int* cur_rates  = (int*)alloc((size_t)NI * 4);
    int* esrc_rates = (int*)alloc((size_t)NEDGE * 4);
    int* deg_rated  = (int*)alloc((size_t)NU * 4);
    int* off_rated  = (int*)alloc((size_t)(NU + 1) * 4);
    int* cur_rated  = (int*)alloc((size_t)NU * 4);
    int* esrc_rated = (int*)alloc((size_t)NEDGE * 4);
    int* deg_fol    = (int*)alloc((size_t)NU * 4);
    int* off_fol    = (int*)alloc((size_t)(NU + 1) * 4);
    int* cur_fol    = (int*)alloc((size_t)NU * 4);
    int* esrc_fol   = (int*)alloc((size_t)NEDGE * 4);
    int* bsum = (int*)alloc(1024 * 4);
    int* boff = (int*)alloc(1024 * 4);

    short* pWu      = (short*)alloc(8 * 2 * 64 * 8 * 2);
    short* pWi      = (short*)alloc(8 * 4 * 64 * 8 * 2);
    short* pRates0  = (short*)alloc(8 * 8 * 64 * 8 * 2);
    short* pUser0   = (short*)alloc(8 * 12 * 64 * 8 * 2);   // [Wl_rated;Wl_fol;Wr_sum]
    short* pFoldA   = (short*)alloc(2 * 4 * 64 * 8 * 2);
    short* pFoldB   = (short*)alloc(1 * 4 * 64 * 8 * 2);
    float* bSum0    = (float*)alloc(128 * 4);
    float* bias16   = (float*)alloc(16 * 4);
    if (used > ws_size) return;   // diagnostic signature: output stays zero

    auto build_csr = [&](const int* dstA, const int* srcA, int N, int* deg, int* off,
                         int* cur, int* esrc) {
        hipMemsetAsync(deg, 0, (size_t)N * 4, stream);
        k_hist<<<(NEDGE + 255) / 256, 256, 0, stream>>>(dstA, deg, NEDGE);
        int nb = (N + 1023) / 1024;
        k_block_sums<<<nb, 1024, 0, stream>>>(deg, bsum, N);
        k_scan_bsums<<<1, 1024, 0, stream>>>(bsum, boff, off, nb, N);
        k_scan_write<<<nb, 1024, 0, stream>>>(deg, boff, off, cur, N);
        k_fill<<<(NEDGE + 255) / 256, 256, 0, stream>>>(srcA, dstA, cur, esrc, NEDGE);
    };

    build_csr(dst_rates, src_rates, NI, deg_rates, off_rates, cur_rates, esrc_rates);
    build_csr(dst_rated, src_rated, NU, deg_rated, off_rated, cur_rated, esrc_rated);
    build_csr(dst_fol,   src_fol,   NU, deg_fol,   off_fol,   cur_fol,   esrc_fol);

    // ---- weight packing ----
    k_pack<<<16, 64, 0, stream>>>(pWu, W_in_user, nullptr, nullptr, 64, 0, 128);
    k_pack<<<32, 64, 0, stream>>>(pWi, W_in_item, nullptr, nullptr, 128, 0, 128);
    k_pack<<<64, 64, 0, stream>>>(pRates0, Wl_rates, Wr_rates, nullptr, 128, 128, 128);
    k_pack3<<<96, 64, 0, stream>>>(pUser0, Wl_rated, Wl_fol, Wr_rated, Wr_fol);
    k_addbias<<<1, 128, 0, stream>>>(bSum0, bl_rated, bl_fol);
    k_foldpack<<<4, 64, 0, stream>>>(pFoldA, Wl_fol + HH,   nullptr,      W_out, 0);
    k_foldpack<<<4, 64, 0, stream>>>(pFoldA, Wr_rated + HH, Wr_fol + HH,  W_out, 1);
    k_foldpack<<<4, 64, 0, stream>>>(pFoldB, Wl_rated + HH, nullptr,      W_out, 0);
    k_bfold<<<1, 16, 0, stream>>>(bias16, bl_rated + 128, bl_fol + 128, W_out, b_out);

    const int gU2 = (NU + 127) / 128;
    const int gI2 = (NI + 127) / 128;
    const int gU  = (NU + 63) / 64;
    const int gI  = (NI + 63) / 64;

    // ---- input projections (fp32 A) ----
    k_mm<2, true, false, 8><<<gU2, 256, 0, stream>>>(x_user, pWu, b_in_user, hu_a, NU);
    k_mm<4, true, false, 8><<<gI2, 256, 0, stream>>>(x_item, pWi, b_in_item, hi_a, NI);

    // ---- layer 0 (leaky): item update + merged user update ----
    k_sage<4, true><<<gI, 256, 0, stream>>>(
        hu_a, hi_a, off_rates, esrc_rates, pRates0, bl_rates, hi_b, NI);
    k_sage2<true><<<gU, 256, 0, stream>>>(
        hi_a, hu_a, off_rated, esrc_rated, off_fol, esrc_fol, pUser0, bSum0, hu_b, NU);

    // ---- layer 1: dense 16-dim projections (item SAGE dead code; removed) ----
    k_mm<4, false, false, 2><<<gU2, 256, 0, stream>>>(hu_b, pFoldA, nullptr, YZ, NU);
    k_mm<4, false, false, 1><<<gI2, 256, 0, stream>>>(hi_b, pFoldB, nullptr, YI, NI);

    // ---- final: dual 16-dim gather-mean + residual + bias -> fp32 out ----
    k_out<<<(NU + 127) / 128, 256, 0, stream>>>(
        YZ, YI, off_fol, esrc_fol, off_rated, esrc_rated, bias16, out, NU);
}

// Round 9
// 782.616 us; speedup vs baseline: 1.3714x; 1.2490x over previous
//
#include <hip/hip_runtime.h>
#include <cstdint>

typedef short short8 __attribute__((ext_vector_type(8)));
typedef float floatx4 __attribute__((ext_vector_type(4)));

constexpr int NU = 200000;   // N_USER
constexpr int NI = 100000;   // N_ITEM
constexpr int NEDGE = 1000000;
constexpr int HD = 128;
constexpr int HH = HD * HD;
constexpr int BUK = 1024;    // nodes per place-bucket
constexpr int EPB = 4096;    // edges per partition block
constexpr int EPT = 16;      // edges per thread (256 thr)
constexpr int MAXBUK = 256;  // >= ceil(NU/BUK)=196

// ---- bf16 bit helpers ----
__device__ __forceinline__ float bits2f(short s) {
    return __uint_as_float(((unsigned int)(unsigned short)s) << 16);
}
__device__ __forceinline__ short f2bits(float f) {
    unsigned int u = __float_as_uint(f);
    unsigned int lsb = (u >> 16) & 1u;
    u += 0x7fffu + lsb;   // round-to-nearest-even
    return (short)(u >> 16);
}

// ================= CSR build =================
__global__ void k_hist(const int* __restrict__ dst, int* __restrict__ deg, int E) {
    int e = blockIdx.x * 256 + threadIdx.x;
    if (e < E) atomicAdd(&deg[dst[e]], 1);
}

__global__ void k_block_sums(const int* __restrict__ deg, int* __restrict__ bsum, int N) {
    __shared__ int s[1024];
    int t = threadIdx.x;
    int i = blockIdx.x * 1024 + t;
    s[t] = (i < N) ? deg[i] : 0;
    __syncthreads();
    for (int d = 512; d > 0; d >>= 1) {
        if (t < d) s[t] += s[t + d];
        __syncthreads();
    }
    if (t == 0) bsum[blockIdx.x] = s[0];
}

__global__ void k_scan_bsums(const int* __restrict__ bsum, int* __restrict__ boff,
                             int* __restrict__ off, int nb, int N) {
    __shared__ int s[1024];
    int t = threadIdx.x;
    int v = (t < nb) ? bsum[t] : 0;
    s[t] = v;
    __syncthreads();
    for (int d = 1; d < 1024; d <<= 1) {
        int u = (t >= d) ? s[t - d] : 0;
        __syncthreads();
        s[t] += u;
        __syncthreads();
    }
    if (t < nb) boff[t] = s[t] - v;
    if (t == nb - 1) off[N] = s[t];
}

__global__ void k_scan_write(const int* __restrict__ deg, const int* __restrict__ boff,
                             int* __restrict__ off, int N) {
    __shared__ int s[1024];
    int t = threadIdx.x;
    int i = blockIdx.x * 1024 + t;
    int v = (i < N) ? deg[i] : 0;
    s[t] = v;
    __syncthreads();
    for (int d = 1; d < 1024; d <<= 1) {
        int u = (t >= d) ? s[t - d] : 0;
        __syncthreads();
        s[t] += u;
        __syncthreads();
    }
    if (i < N) off[i] = boff[blockIdx.x] + s[t] - v;
}

// bucket cursors seeded from off at BUK stride
__global__ void k_initcur(const int* __restrict__ off, int* __restrict__ bcur,
                          int nbuk, int N) {
    int b = blockIdx.x * 256 + threadIdx.x;
    if (b < nbuk) bcur[b] = off[min(b * BUK, N)];
}

// pass A: LDS-privatized rank + one global atomic per (block,bucket).
// r4's k_part failed on 640-deep GLOBAL cursor contention; this keeps the
// per-edge atomics in LDS (contention-free-ish) and does ~196 global atomics/block.
__global__ __launch_bounds__(256) void k_partA(const int* __restrict__ src,
                                               const int* __restrict__ dst,
                                               int* __restrict__ bcur,
                                               int2* __restrict__ pairs, int E) {
    __shared__ int cnt[MAXBUK];
    __shared__ int base[MAXBUK];
    int t = threadIdx.x;
    for (int b = t; b < MAXBUK; b += 256) cnt[b] = 0;
    __syncthreads();
    const int e0 = blockIdx.x * EPB + t * EPT;
    int dv[EPT], sv[EPT], rk[EPT];
#pragma unroll
    for (int i = 0; i < EPT; ++i) {
        int e = e0 + i;
        bool ok = e < E;
        dv[i] = ok ? dst[e] : 0;
        sv[i] = ok ? src[e] : 0;
    }
#pragma unroll
    for (int i = 0; i < EPT; ++i) {
        rk[i] = (e0 + i < E) ? atomicAdd(&cnt[dv[i] >> 10], 1) : 0;
    }
    __syncthreads();
    for (int b = t; b < MAXBUK; b += 256) {
        int c = cnt[b];
        base[b] = c ? atomicAdd(&bcur[b], c) : 0;
    }
    __syncthreads();
#pragma unroll
    for (int i = 0; i < EPT; ++i) {
        if (e0 + i < E) {
            int b = dv[i] >> 10;
            pairs[base[b] + rk[i]] = make_int2(sv[i], dv[i]);
        }
    }
}

// pass B: one block per bucket; LDS per-node cursors; esrc region block-private.
__global__ __launch_bounds__(256) void k_placeB(const int2* __restrict__ pairs,
                                                const int* __restrict__ off,
                                                int* __restrict__ esrc, int N) {
    __shared__ int scur[BUK];
    int n0 = blockIdx.x * BUK;
    int nend = min(n0 + BUK, N);
    int t = threadIdx.x;
    for (int i = t; i < BUK; i += 256) scur[i] = (n0 + i < nend) ? off[n0 + i] : 0;
    __syncthreads();
    int s = off[n0], e = off[nend];
    for (int j = s + t; j < e; j += 256) {
        int2 p = pairs[j];
        int pos = atomicAdd(&scur[p.y - n0], 1);
        esrc[pos] = p.x;
    }
}

// ================= weight pack (fp32 -> bf16 fragment order) =================
__global__ void k_pack(short* __restrict__ dst, const float* __restrict__ A,
                       const float* __restrict__ B, const float* __restrict__ B2,
                       int KA, int KBr, int NCOL) {
    int l = threadIdx.x;
    int kbt = (KA + KBr) >> 5;
    int nt = blockIdx.x / kbt;
    int kb = blockIdx.x % kbt;
    int col = nt * 16 + (l & 15);
    int k0 = kb * 32 + (l >> 4) * 8;
    short8 o;
#pragma unroll
    for (int j = 0; j < 8; ++j) {
        int k = k0 + j;
        float f;
        if (k < KA) {
            f = A[(size_t)k * NCOL + col];
        } else {
            int k2 = k - KA;
            f = B[(size_t)k2 * NCOL + col];
            if (B2) f += B2[(size_t)k2 * NCOL + col];
        }
        o[j] = f2bits(f);
    }
    *(short8*)(dst + ((size_t)blockIdx.x * 64 + l) * 8) = o;
}

// 3-section pack: W2 = [A(128) ; B(128) ; C1+C2(128)], KBT=12, NCOL=128
__global__ void k_pack3(short* __restrict__ dst, const float* __restrict__ A,
                        const float* __restrict__ B, const float* __restrict__ C1,
                        const float* __restrict__ C2) {
    int l = threadIdx.x;
    constexpr int kbt = 12;
    int nt = blockIdx.x / kbt;
    int kb = blockIdx.x % kbt;
    int col = nt * 16 + (l & 15);
    int k0 = kb * 32 + (l >> 4) * 8;
    short8 o;
#pragma unroll
    for (int j = 0; j < 8; ++j) {
        int k = k0 + j;
        float f;
        if (k < 128) f = A[(size_t)k * 128 + col];
        else if (k < 256) f = B[(size_t)(k - 128) * 128 + col];
        else f = C1[(size_t)(k - 256) * 128 + col] + C2[(size_t)(k - 256) * 128 + col];
        o[j] = f2bits(f);
    }
    *(short8*)(dst + ((size_t)blockIdx.x * 64 + l) * 8) = o;
}

// transposed fold: WT[c][k] = sum_t (Wa[k][t] (+Wb[k][t])) * Wo[t][c]   (fp32)
// launch <<<128, 16>>>: blockIdx = k, thread = c
__global__ void k_foldT(float* __restrict__ WT, const float* __restrict__ Wa,
                        const float* __restrict__ Wb, const float* __restrict__ Wo) {
    int k = blockIdx.x;
    int c = threadIdx.x;
    float a = 0.f;
    for (int t = 0; t < 128; ++t) {
        float w = Wa[(size_t)k * 128 + t];
        if (Wb) w += Wb[(size_t)k * 128 + t];
        a += w * Wo[t * 16 + c];
    }
    WT[c * 128 + k] = a;
}

__global__ void k_bfold(float* __restrict__ dst, const float* __restrict__ bl1,
                        const float* __restrict__ bl2, const float* __restrict__ Wo,
                        const float* __restrict__ bo) {
    int c = threadIdx.x;
    float a = 0.f;
    for (int t = 0; t < 128; ++t) a += (bl1[t] + bl2[t]) * Wo[t * 16 + c];
    dst[c] = a + bo[c];
}

__global__ void k_addbias(float* __restrict__ dst, const float* __restrict__ a,
                          const float* __restrict__ b) {
    int i = threadIdx.x;
    dst[i] = a[i] + b[i];
}

// ---- shared gather-mean helper ----
__device__ __forceinline__ void gather_mean(const short* __restrict__ Xsrc,
                                            const int* __restrict__ off,
                                            const int* __restrict__ esrc,
                                            int ar, int ksub, float macc[4][8]) {
#pragma unroll
    for (int kb = 0; kb < 4; ++kb)
#pragma unroll
        for (int i = 0; i < 8; ++i) macc[kb][i] = 0.f;

    const int s = off[ar], e = off[ar + 1];
    int j = s;
    for (; j + 4 <= e; j += 4) {
        const int i0 = esrc[j], i1 = esrc[j + 1], i2 = esrc[j + 2], i3 = esrc[j + 3];
        const short* p0 = Xsrc + (size_t)i0 * HD + ksub;
        const short* p1 = Xsrc + (size_t)i1 * HD + ksub;
        const short* p2 = Xsrc + (size_t)i2 * HD + ksub;
        const short* p3 = Xsrc + (size_t)i3 * HD + ksub;
        short8 v0[4], v1[4], v2[4], v3[4];
#pragma unroll
        for (int kb = 0; kb < 4; ++kb) {
            v0[kb] = *(const short8*)(p0 + kb * 32);
            v1[kb] = *(const short8*)(p1 + kb * 32);
            v2[kb] = *(const short8*)(p2 + kb * 32);
            v3[kb] = *(const short8*)(p3 + kb * 32);
        }
#pragma unroll
        for (int kb = 0; kb < 4; ++kb)
#pragma unroll
            for (int i = 0; i < 8; ++i)
                macc[kb][i] += (bits2f(v0[kb][i]) + bits2f(v1[kb][i]))
                             + (bits2f(v2[kb][i]) + bits2f(v3[kb][i]));
    }
    for (; j < e; ++j) {
        const short* xp = Xsrc + (size_t)esrc[j] * HD + ksub;
#pragma unroll
        for (int kb = 0; kb < 4; ++kb) {
            short8 v = *(const short8*)(xp + kb * 32);
#pragma unroll
            for (int i = 0; i < 8; ++i) macc[kb][i] += bits2f(v[i]);
        }
    }
    const int d = e - s;
    const float inv = 1.f / (float)(d > 0 ? d : 1);
#pragma unroll
    for (int kb = 0; kb < 4; ++kb)
#pragma unroll
        for (int i = 0; i < 8; ++i) macc[kb][i] *= inv;
}

// ---- fused fold-project epilogue: Y[row][c] = sum_k leaky(h)[row][k]*P[k][c] ----
// h is held as C-fragments: lane (group g=lane>>4, col=lane&15) has rows g*4+r,
// k = nt*16+col. Per c: per-lane partial over nt, then 16-lane butterfly.
template <int NC>
__device__ __forceinline__ void fold_write(const floatx4* acc, const float* __restrict__ bias,
                                           const float* __restrict__ WT, bool leaky,
                                           short* __restrict__ Y, int r0, int lane, int M) {
    const int colL = lane & 15;
    const int rbase = r0 + (lane >> 4) * 4;
    float v[8][4];
#pragma unroll
    for (int nt = 0; nt < 8; ++nt) {
        float bv = bias ? bias[nt * 16 + colL] : 0.f;
#pragma unroll
        for (int r = 0; r < 4; ++r) {
            float x = acc[nt][r] + bv;
            v[nt][r] = (leaky && x < 0.f) ? 0.01f * x : x;
        }
    }
    for (int c = 0; c < NC; ++c) {
        float p0 = 0.f, p1 = 0.f, p2 = 0.f, p3 = 0.f;
#pragma unroll
        for (int nt = 0; nt < 8; ++nt) {
            float w = WT[c * 128 + nt * 16 + colL];
            p0 += v[nt][0] * w;
            p1 += v[nt][1] * w;
            p2 += v[nt][2] * w;
            p3 += v[nt][3] * w;
        }
#pragma unroll
        for (int m = 1; m < 16; m <<= 1) {
            p0 += __shfl_xor(p0, m, 16);
            p1 += __shfl_xor(p1, m, 16);
            p2 += __shfl_xor(p2, m, 16);
            p3 += __shfl_xor(p3, m, 16);
        }
        if (colL == (c & 15)) {
            float pr[4] = {p0, p1, p2, p3};
#pragma unroll
            for (int r = 0; r < 4; ++r) {
                int row = rbase + r;
                if (row < M) Y[(size_t)row * NC + c] = f2bits(pr[r]);
            }
        }
    }
}

// ================= fused SAGE (items): gather + MFMA + leaky + fold -> YI[NI][16] =================
__global__ __launch_bounds__(256) void k_sageI(const short* __restrict__ Xsrc,
                                               const short* __restrict__ A2,
                                               const int* __restrict__ off,
                                               const int* __restrict__ esrc,
                                               const short* __restrict__ Wp,
                                               const float* __restrict__ bias,
                                               const float* __restrict__ WT,
                                               short* __restrict__ YI, int M) {
    constexpr int KBT = 8;
    const int lane = threadIdx.x & 63;
    const int wv = threadIdx.x >> 6;
    const int r0 = blockIdx.x * 64 + wv * 16;

    int ar = r0 + (lane & 15);
    if (ar >= M) ar = M - 1;
    const int ksub = (lane >> 4) * 8;

    float macc[4][8];
    gather_mean(Xsrc, off, esrc, ar, ksub, macc);

    short8 afrag[KBT];
#pragma unroll
    for (int kb = 0; kb < 4; ++kb) {
        short8 f;
#pragma unroll
        for (int i = 0; i < 8; ++i) f[i] = f2bits(macc[kb][i]);
        afrag[kb] = f;
    }
    {
        const short* p = A2 + (size_t)ar * HD + ksub;
#pragma unroll
        for (int kb = 0; kb < 4; ++kb) afrag[4 + kb] = *(const short8*)(p + kb * 32);
    }

    floatx4 acc[8];
#pragma unroll
    for (int nt = 0; nt < 8; ++nt) acc[nt] = (floatx4){0.f, 0.f, 0.f, 0.f};
    const short8* wp = (const short8*)Wp + lane;
#pragma unroll
    for (int nt = 0; nt < 8; ++nt)
#pragma unroll
        for (int kb = 0; kb < KBT; ++kb) {
            short8 b = wp[(nt * KBT + kb) * 64];
            acc[nt] = __builtin_amdgcn_mfma_f32_16x16x32_bf16(afrag[kb], b, acc[nt], 0, 0, 0);
        }

    fold_write<16>(acc, bias, WT, true, YI, r0, lane, M);
}

// ================= fused dual-gather SAGE (users) -> YZ[NU][32] =================
__global__ __launch_bounds__(256) void k_sageU(const short* __restrict__ Hi,
                                               const short* __restrict__ Hu,
                                               const int* __restrict__ off_r,
                                               const int* __restrict__ esrc_r,
                                               const int* __restrict__ off_f,
                                               const int* __restrict__ esrc_f,
                                               const short* __restrict__ Wp,
                                               const float* __restrict__ bias,
                                               const float* __restrict__ WT,
                                               short* __restrict__ YZ, int M) {
    constexpr int KBT = 12;
    const int lane = threadIdx.x & 63;
    const int wv = threadIdx.x >> 6;
    const int r0 = blockIdx.x * 64 + wv * 16;

    int ar = r0 + (lane & 15);
    if (ar >= M) ar = M - 1;
    const int ksub = (lane >> 4) * 8;

    short8 afrag[KBT];
    {
        float macc[4][8];
        gather_mean(Hi, off_r, esrc_r, ar, ksub, macc);
#pragma unroll
        for (int kb = 0; kb < 4; ++kb) {
            short8 f;
#pragma unroll
            for (int i = 0; i < 8; ++i) f[i] = f2bits(macc[kb][i]);
            afrag[kb] = f;
        }
        gather_mean(Hu, off_f, esrc_f, ar, ksub, macc);
#pragma unroll
        for (int kb = 0; kb < 4; ++kb) {
            short8 f;
#pragma unroll
            for (int i = 0; i < 8; ++i) f[i] = f2bits(macc[kb][i]);
            afrag[4 + kb] = f;
        }
    }
    {
        const short* p = Hu + (size_t)ar * HD + ksub;
#pragma unroll
        for (int kb = 0; kb < 4; ++kb) afrag[8 + kb] = *(const short8*)(p + kb * 32);
    }

    floatx4 acc[8];
#pragma unroll
    for (int nt = 0; nt < 8; ++nt) acc[nt] = (floatx4){0.f, 0.f, 0.f, 0.f};
    const short8* wp = (const short8*)Wp + lane;
#pragma unroll
    for (int nt = 0; nt < 8; ++nt)
#pragma unroll
        for (int kb = 0; kb < KBT; ++kb) {
            short8 b = wp[(nt * KBT + kb) * 64];
            acc[nt] = __builtin_amdgcn_mfma_f32_16x16x32_bf16(afrag[kb], b, acc[nt], 0, 0, 0);
        }

    fold_write<32>(acc, bias, WT, true, YZ, r0, lane, M);
}

// ================= plain MFMA GEMM (input projections): 32 rows/wave =================
template <int KB1, int NT>
__global__ __launch_bounds__(256) void k_mm(const float* __restrict__ A1,
                                            const short* __restrict__ Wp,
                                            const float* __restrict__ bias,
                                            short* __restrict__ C, int M) {
    constexpr int KBT = KB1;
    const int lane = threadIdx.x & 63;
    const int wv = threadIdx.x >> 6;
    const int r0 = blockIdx.x * 128 + wv * 32;

    const int ksub = (lane >> 4) * 8;
    short8 afrag[2][KBT];
#pragma unroll
    for (int h = 0; h < 2; ++h) {
        int ar = r0 + h * 16 + (lane & 15);
        if (ar >= M) ar = M - 1;
        const float* p = A1 + (size_t)ar * (KB1 * 32) + ksub;
#pragma unroll
        for (int kb = 0; kb < KB1; ++kb) {
            short8 f;
#pragma unroll
            for (int j = 0; j < 8; ++j) f[j] = f2bits(p[kb * 32 + j]);
            afrag[h][kb] = f;
        }
    }

    floatx4 acc[2][NT];
#pragma unroll
    for (int h = 0; h < 2; ++h)
#pragma unroll
        for (int nt = 0; nt < NT; ++nt) acc[h][nt] = (floatx4){0.f, 0.f, 0.f, 0.f};

    const short8* wp = (const short8*)Wp + lane;
#pragma unroll
    for (int nt = 0; nt < NT; ++nt)
#pragma unroll
        for (int kb = 0; kb < KBT; ++kb) {
            short8 b = wp[(nt * KBT + kb) * 64];
            acc[0][nt] = __builtin_amdgcn_mfma_f32_16x16x32_bf16(afrag[0][kb], b, acc[0][nt], 0, 0, 0);
            acc[1][nt] = __builtin_amdgcn_mfma_f32_16x16x32_bf16(afrag[1][kb], b, acc[1][nt], 0, 0, 0);
        }

    const int col = lane & 15;
#pragma unroll
    for (int h = 0; h < 2; ++h) {
        const int rbase = r0 + h * 16 + (lane >> 4) * 4;
#pragma unroll
        for (int nt = 0; nt < NT; ++nt) {
            float bv = bias ? bias[nt * 16 + col] : 0.f;
#pragma unroll
            for (int r = 0; r < 4; ++r) {
                int row = rbase + r;
                if (row < M)
                    C[(size_t)row * (NT * 16) + nt * 16 + col] = f2bits(acc[h][nt][r] + bv);
            }
        }
    }
}

// ================= final output =================
__global__ __launch_bounds__(256) void k_out(const short* __restrict__ YZ,
                                             const short* __restrict__ YI,
                                             const int* __restrict__ off_f,
                                             const int* __restrict__ esrc_f,
                                             const int* __restrict__ off_r,
                                             const int* __restrict__ esrc_r,
                                             const float* __restrict__ bias16,
                                             float* __restrict__ out, int N) {
    int t = threadIdx.x;
    int node = blockIdx.x * 128 + (t >> 1);
    int half = t & 1;
    if (node >= N) return;
    const int c0 = half * 8;

    float a[8] = {0.f, 0.f, 0.f, 0.f, 0.f, 0.f, 0.f, 0.f};
    {
        const int s = off_f[node], e = off_f[node + 1];
        int j = s;
        for (; j + 4 <= e; j += 4) {
            short8 v0 = *(const short8*)(YZ + (size_t)esrc_f[j] * 32 + c0);
            short8 v1 = *(const short8*)(YZ + (size_t)esrc_f[j + 1] * 32 + c0);
            short8 v2 = *(const short8*)(YZ + (size_t)esrc_f[j + 2] * 32 + c0);
            short8 v3 = *(const short8*)(YZ + (size_t)esrc_f[j + 3] * 32 + c0);
#pragma unroll
            for (int i = 0; i < 8; ++i)
                a[i] += (bits2f(v0[i]) + bits2f(v1[i])) + (bits2f(v2[i]) + bits2f(v3[i]));
        }
        for (; j < e; ++j) {
            short8 v = *(const short8*)(YZ + (size_t)esrc_f[j] * 32 + c0);
#pragma unroll
            for (int i = 0; i < 8; ++i) a[i] += bits2f(v[i]);
        }
        int d = e - s;
        float inv = 1.f / (float)(d > 0 ? d : 1);
#pragma unroll
        for (int i = 0; i < 8; ++i) a[i] *= inv;
    }
    {
        float b[8] = {0.f, 0.f, 0.f, 0.f, 0.f, 0.f, 0.f, 0.f};
        const int s = off_r[node], e = off_r[node + 1];
        int j = s;
        for (; j + 4 <= e; j += 4) {
            short8 v0 = *(const short8*)(YI + (size_t)esrc_r[j] * 16 + c0);
            short8 v1 = *(const short8*)(YI + (size_t)esrc_r[j + 1] * 16 + c0);
            short8 v2 = *(const short8*)(YI + (size_t)esrc_r[j + 2] * 16 + c0);
            short8 v3 = *(const short8*)(YI + (size_t)esrc_r[j + 3] * 16 + c0);
#pragma unroll
            for (int i = 0; i < 8; ++i)
                b[i] += (bits2f(v0[i]) + bits2f(v1[i])) + (bits2f(v2[i]) + bits2f(v3[i]));
        }
        for (; j < e; ++j) {
            short8 v = *(const short8*)(YI + (size_t)esrc_r[j] * 16 + c0);
#pragma unroll
            for (int i = 0; i < 8; ++i) b[i] += bits2f(v[i]);
        }
        int d = e - s;
        float inv = 1.f / (float)(d > 0 ? d : 1);
#pragma unroll
        for (int i = 0; i < 8; ++i) a[i] += b[i] * inv;
    }
    short8 z = *(const short8*)(YZ + (size_t)node * 32 + 16 + c0);
#pragma unroll
    for (int i = 0; i < 8; ++i)
        out[(size_t)node * 16 + c0 + i] = a[i] + bits2f(z[i]) + bias16[c0 + i];
}

// ================= launch =================
extern "C" void kernel_launch(void* const* d_in, const int* in_sizes, int n_in,
                              void* d_out, int out_size, void* d_ws, size_t ws_size,
                              hipStream_t stream) {
    const float* x_user    = (const float*)d_in[0];
    const float* x_item    = (const float*)d_in[1];
    const int* src_rates   = (const int*)d_in[2];
    const int* dst_rates   = (const int*)d_in[3];
    const int* src_rated   = (const int*)d_in[4];
    const int* dst_rated   = (const int*)d_in[5];
    const int* src_fol     = (const int*)d_in[6];
    const int* dst_fol     = (const int*)d_in[7];
    const float* W_in_user = (const float*)d_in[8];
    const float* b_in_user = (const float*)d_in[9];
    const float* W_in_item = (const float*)d_in[10];
    const float* b_in_item = (const float*)d_in[11];
    const float* Wl_rates  = (const float*)d_in[12];
    const float* bl_rates  = (const float*)d_in[13];
    const float* Wr_rates  = (const float*)d_in[14];
    const float* Wl_rated  = (const float*)d_in[15];
    const float* bl_rated  = (const float*)d_in[16];
    const float* Wr_rated  = (const float*)d_in[17];
    const float* Wl_fol    = (const float*)d_in[18];
    const float* bl_fol    = (const float*)d_in[19];
    const float* Wr_fol    = (const float*)d_in[20];
    const float* W_out     = (const float*)d_in[21];
    const float* b_out     = (const float*)d_in[22];
    float* out = (float*)d_out;

    char* w = (char*)d_ws;
    size_t used = 0;
    auto alloc = [&](size_t bytes) -> void* {
        void* p = w + used;
        used += (bytes + 255) & ~(size_t)255;
        return p;
    };
    short* hu_a = (short*)alloc((size_t)NU * HD * 2);
    short* hi_a = (short*)alloc((size_t)NI * HD * 2);
    short* YZ   = (short*)alloc((size_t)NU * 32 * 2);
    short* YI   = (short*)alloc((size_t)NI * 16 * 2);

    int* deg_rates  = (int*)alloc((size_t)NI * 4);
    int* off_rates  = (int*)alloc((size_t)(NI + 1) * 4);
    int* esrc_rates = (int*)alloc((size_t)NEDGE * 4);
    int* deg_rated  = (int*)alloc((size_t)NU * 4);
    int* off_rated  = (int*)alloc((size_t)(NU + 1) * 4);
    int* esrc_rated = (int*)alloc((size_t)NEDGE * 4);
    int* deg_fol    = (int*)alloc((size_t)NU * 4);
    int* off_fol    = (int*)alloc((size_t)(NU + 1) * 4);
    int* esrc_fol   = (int*)alloc((size_t)NEDGE * 4);
    int2* pairs     = (int2*)alloc((size_t)NEDGE * 8);
    int* bcur       = (int*)alloc(MAXBUK * 4);
    int* bsum = (int*)alloc(1024 * 4);
    int* boff = (int*)alloc(1024 * 4);

    short* pWu    = (short*)alloc(8 * 2 * 64 * 8 * 2);
    short* pWi    = (short*)alloc(8 * 4 * 64 * 8 * 2);
    short* pRates0 = (short*)alloc(8 * 8 * 64 * 8 * 2);
    short* pUser0  = (short*)alloc(8 * 12 * 64 * 8 * 2);   // [Wl_rated;Wl_fol;Wr_sum]
    float* WT_A   = (float*)alloc(32 * 128 * 4);  // [P_fol | P_wrsum]^T
    float* WT_B   = (float*)alloc(16 * 128 * 4);  // P_rated^T
    float* bSum0  = (float*)alloc(128 * 4);
    float* bias16 = (float*)alloc(16 * 4);
    if (used > ws_size) return;   // diagnostic signature: output stays zero

    auto build_csr = [&](const int* dstA, const int* srcA, int N, int* deg, int* off,
                         int* esrc) {
        hipMemsetAsync(deg, 0, (size_t)N * 4, stream);
        k_hist<<<(NEDGE + 255) / 256, 256, 0, stream>>>(dstA, deg, NEDGE);
        int nb = (N + 1023) / 1024;
        k_block_sums<<<nb, 1024, 0, stream>>>(deg, bsum, N);
        k_scan_bsums<<<1, 1024, 0, stream>>>(bsum, boff, off, nb, N);
        k_scan_write<<<nb, 1024, 0, stream>>>(deg, boff, off, N);
        int nbuk = (N + BUK - 1) / BUK;
        k_initcur<<<1, 256, 0, stream>>>(off, bcur, nbuk, N);
        k_partA<<<(NEDGE + EPB - 1) / EPB, 256, 0, stream>>>(srcA, dstA, bcur, pairs, NEDGE);
        k_placeB<<<nbuk, 256, 0, stream>>>(pairs, off, esrc, N);
    };

    build_csr(dst_rates, src_rates, NI, deg_rates, off_rates, esrc_rates);
    build_csr(dst_rated, src_rated, NU, deg_rated, off_rated, esrc_rated);
    build_csr(dst_fol,   src_fol,   NU, deg_fol,   off_fol,   esrc_fol);

    // ---- weight packing ----
    k_pack<<<16, 64, 0, stream>>>(pWu, W_in_user, nullptr, nullptr, 64, 0, 128);
    k_pack<<<32, 64, 0, stream>>>(pWi, W_in_item, nullptr, nullptr, 128, 0, 128);
    k_pack<<<64, 64, 0, stream>>>(pRates0, Wl_rates, Wr_rates, nullptr, 128, 128, 128);
    k_pack3<<<96, 64, 0, stream>>>(pUser0, Wl_rated, Wl_fol, Wr_rated, Wr_fol);
    k_addbias<<<1, 128, 0, stream>>>(bSum0, bl_rated, bl_fol);
    k_foldT<<<128, 16, 0, stream>>>(WT_A,       Wl_fol + HH,   nullptr,     W_out);
    k_foldT<<<128, 16, 0, stream>>>(WT_A + 2048, Wr_rated + HH, Wr_fol + HH, W_out);
    k_foldT<<<128, 16, 0, stream>>>(WT_B,       Wl_rated + HH, nullptr,     W_out);
    k_bfold<<<1, 16, 0, stream>>>(bias16, bl_rated + 128, bl_fol + 128, W_out, b_out);

    const int gU2 = (NU + 127) / 128;
    const int gI2 = (NI + 127) / 128;
    const int gU  = (NU + 63) / 64;
    const int gI  = (NI + 63) / 64;

    // ---- input projections (fp32 A) ----
    k_mm<2, 8><<<gU2, 256, 0, stream>>>(x_user, pWu, b_in_user, hu_a, NU);
    k_mm<4, 8><<<gI2, 256, 0, stream>>>(x_item, pWi, b_in_item, hi_a, NI);

    // ---- layer 0 + fused layer-1 fold projections ----
    k_sageI<<<gI, 256, 0, stream>>>(
        hu_a, hi_a, off_rates, esrc_rates, pRates0, bl_rates, WT_B, YI, NI);
    k_sageU<<<gU, 256, 0, stream>>>(
        hi_a, hu_a, off_rated, esrc_rated, off_fol, esrc_fol, pUser0, bSum0, WT_A, YZ, NU);

    // ---- final: dual 16-dim gather-mean + residual + bias -> fp32 out ----
    k_out<<<(NU + 127) / 128, 256, 0, stream>>>(
        YZ, YI, off_fol, esrc_fol, off_rated, esrc_rated, bias16, out, NU);
}

// Round 10
// 613.155 us; speedup vs baseline: 1.7505x; 1.2764x over previous
//
#include <hip/hip_runtime.h>
#include <cstdint>

typedef short short8 __attribute__((ext_vector_type(8)));
typedef float floatx4 __attribute__((ext_vector_type(4)));

constexpr int NU = 200000;   // N_USER
constexpr int NI = 100000;   // N_ITEM
constexpr int NEDGE = 1000000;
constexpr int HD = 128;
constexpr int HH = HD * HD;
constexpr int BUK = 1024;    // nodes per place-bucket
constexpr int EPB = 4096;    // edges per partition block
constexpr int EPT = 16;      // edges per thread (256 thr)
constexpr int MAXBUK = 256;  // >= ceil(NU/BUK)=196
constexpr int LROW = 136;    // LDS row stride in shorts (128 + 8 pad)

// ---- bf16 bit helpers ----
__device__ __forceinline__ float bits2f(short s) {
    return __uint_as_float(((unsigned int)(unsigned short)s) << 16);
}
__device__ __forceinline__ short f2bits(float f) {
    unsigned int u = __float_as_uint(f);
    unsigned int lsb = (u >> 16) & 1u;
    u += 0x7fffu + lsb;   // round-to-nearest-even
    return (short)(u >> 16);
}

// ================= CSR build =================
__global__ void k_hist(const int* __restrict__ dst, int* __restrict__ deg, int E) {
    int e = blockIdx.x * 256 + threadIdx.x;
    if (e < E) atomicAdd(&deg[dst[e]], 1);
}

__global__ void k_block_sums(const int* __restrict__ deg, int* __restrict__ bsum, int N) {
    __shared__ int s[1024];
    int t = threadIdx.x;
    int i = blockIdx.x * 1024 + t;
    s[t] = (i < N) ? deg[i] : 0;
    __syncthreads();
    for (int d = 512; d > 0; d >>= 1) {
        if (t < d) s[t] += s[t + d];
        __syncthreads();
    }
    if (t == 0) bsum[blockIdx.x] = s[0];
}

__global__ void k_scan_bsums(const int* __restrict__ bsum, int* __restrict__ boff,
                             int* __restrict__ off, int nb, int N) {
    __shared__ int s[1024];
    int t = threadIdx.x;
    int v = (t < nb) ? bsum[t] : 0;
    s[t] = v;
    __syncthreads();
    for (int d = 1; d < 1024; d <<= 1) {
        int u = (t >= d) ? s[t - d] : 0;
        __syncthreads();
        s[t] += u;
        __syncthreads();
    }
    if (t < nb) boff[t] = s[t] - v;
    if (t == nb - 1) off[N] = s[t];
}

__global__ void k_scan_write(const int* __restrict__ deg, const int* __restrict__ boff,
                             int* __restrict__ off, int N) {
    __shared__ int s[1024];
    int t = threadIdx.x;
    int i = blockIdx.x * 1024 + t;
    int v = (i < N) ? deg[i] : 0;
    s[t] = v;
    __syncthreads();
    for (int d = 1; d < 1024; d <<= 1) {
        int u = (t >= d) ? s[t - d] : 0;
        __syncthreads();
        s[t] += u;
        __syncthreads();
    }
    if (i < N) off[i] = boff[blockIdx.x] + s[t] - v;
}

__global__ void k_initcur(const int* __restrict__ off, int* __restrict__ bcur,
                          int nbuk, int N) {
    int b = blockIdx.x * 256 + threadIdx.x;
    if (b < nbuk) bcur[b] = off[min(b * BUK, N)];
}

// pass A: LDS-privatized rank + one global atomic per (block,bucket)
__global__ __launch_bounds__(256) void k_partA(const int* __restrict__ src,
                                               const int* __restrict__ dst,
                                               int* __restrict__ bcur,
                                               int2* __restrict__ pairs, int E) {
    __shared__ int cnt[MAXBUK];
    __shared__ int base[MAXBUK];
    int t = threadIdx.x;
    for (int b = t; b < MAXBUK; b += 256) cnt[b] = 0;
    __syncthreads();
    const int e0 = blockIdx.x * EPB + t * EPT;
    int dv[EPT], sv[EPT], rk[EPT];
#pragma unroll
    for (int i = 0; i < EPT; ++i) {
        int e = e0 + i;
        bool ok = e < E;
        dv[i] = ok ? dst[e] : 0;
        sv[i] = ok ? src[e] : 0;
    }
#pragma unroll
    for (int i = 0; i < EPT; ++i) {
        rk[i] = (e0 + i < E) ? atomicAdd(&cnt[dv[i] >> 10], 1) : 0;
    }
    __syncthreads();
    for (int b = t; b < MAXBUK; b += 256) {
        int c = cnt[b];
        base[b] = c ? atomicAdd(&bcur[b], c) : 0;
    }
    __syncthreads();
#pragma unroll
    for (int i = 0; i < EPT; ++i) {
        if (e0 + i < E) {
            int b = dv[i] >> 10;
            pairs[base[b] + rk[i]] = make_int2(sv[i], dv[i]);
        }
    }
}

// pass B: one block per bucket; LDS per-node cursors
__global__ __launch_bounds__(256) void k_placeB(const int2* __restrict__ pairs,
                                                const int* __restrict__ off,
                                                int* __restrict__ esrc, int N) {
    __shared__ int scur[BUK];
    int n0 = blockIdx.x * BUK;
    int nend = min(n0 + BUK, N);
    int t = threadIdx.x;
    for (int i = t; i < BUK; i += 256) scur[i] = (n0 + i < nend) ? off[n0 + i] : 0;
    __syncthreads();
    int s = off[n0], e = off[nend];
    for (int j = s + t; j < e; j += 256) {
        int2 p = pairs[j];
        int pos = atomicAdd(&scur[p.y - n0], 1);
        esrc[pos] = p.x;
    }
}

// ================= weight pack (fp32 -> bf16 fragment order) =================
__global__ void k_pack(short* __restrict__ dst, const float* __restrict__ A,
                       const float* __restrict__ B, const float* __restrict__ B2,
                       int KA, int KBr, int NCOL) {
    int l = threadIdx.x;
    int kbt = (KA + KBr) >> 5;
    int nt = blockIdx.x / kbt;
    int kb = blockIdx.x % kbt;
    int col = nt * 16 + (l & 15);
    int k0 = kb * 32 + (l >> 4) * 8;
    short8 o;
#pragma unroll
    for (int j = 0; j < 8; ++j) {
        int k = k0 + j;
        float f;
        if (k < KA) {
            f = A[(size_t)k * NCOL + col];
        } else {
            int k2 = k - KA;
            f = B[(size_t)k2 * NCOL + col];
            if (B2) f += B2[(size_t)k2 * NCOL + col];
        }
        o[j] = f2bits(f);
    }
    *(short8*)(dst + ((size_t)blockIdx.x * 64 + l) * 8) = o;
}

// 3-section pack: W2 = [A(128) ; B(128) ; C1+C2(128)], KBT=12, NCOL=128
__global__ void k_pack3(short* __restrict__ dst, const float* __restrict__ A,
                        const float* __restrict__ B, const float* __restrict__ C1,
                        const float* __restrict__ C2) {
    int l = threadIdx.x;
    constexpr int kbt = 12;
    int nt = blockIdx.x / kbt;
    int kb = blockIdx.x % kbt;
    int col = nt * 16 + (l & 15);
    int k0 = kb * 32 + (l >> 4) * 8;
    short8 o;
#pragma unroll
    for (int j = 0; j < 8; ++j) {
        int k = k0 + j;
        float f;
        if (k < 128) f = A[(size_t)k * 128 + col];
        else if (k < 256) f = B[(size_t)(k - 128) * 128 + col];
        else f = C1[(size_t)(k - 256) * 128 + col] + C2[(size_t)(k - 256) * 128 + col];
        o[j] = f2bits(f);
    }
    *(short8*)(dst + ((size_t)blockIdx.x * 64 + l) * 8) = o;
}

// folded weight (row-major fp32): dst[k][colOff+c] = sum_t (Wa(+Wb))[k][t] * Wo[t][c]
// launch <<<128, 16>>>
__global__ void k_foldW(float* __restrict__ dst, const float* __restrict__ Wa,
                        const float* __restrict__ Wb, const float* __restrict__ Wo,
                        int colOff, int NC) {
    int k = blockIdx.x;
    int c = threadIdx.x;
    float a = 0.f;
    for (int t = 0; t < 128; ++t) {
        float w = Wa[(size_t)k * 128 + t];
        if (Wb) w += Wb[(size_t)k * 128 + t];
        a += w * Wo[t * 16 + c];
    }
    dst[(size_t)k * NC + colOff + c] = a;
}

__global__ void k_bfold(float* __restrict__ dst, const float* __restrict__ bl1,
                        const float* __restrict__ bl2, const float* __restrict__ Wo,
                        const float* __restrict__ bo) {
    int c = threadIdx.x;
    float a = 0.f;
    for (int t = 0; t < 128; ++t) a += (bl1[t] + bl2[t]) * Wo[t * 16 + c];
    dst[c] = a + bo[c];
}

__global__ void k_addbias(float* __restrict__ dst, const float* __restrict__ a,
                          const float* __restrict__ b) {
    int i = threadIdx.x;
    dst[i] = a[i] + b[i];
}

// ---- shared gather-mean helper ----
__device__ __forceinline__ void gather_mean(const short* __restrict__ Xsrc,
                                            const int* __restrict__ off,
                                            const int* __restrict__ esrc,
                                            int ar, int ksub, float macc[4][8]) {
#pragma unroll
    for (int kb = 0; kb < 4; ++kb)
#pragma unroll
        for (int i = 0; i < 8; ++i) macc[kb][i] = 0.f;

    const int s = off[ar], e = off[ar + 1];
    int j = s;
    for (; j + 4 <= e; j += 4) {
        const int i0 = esrc[j], i1 = esrc[j + 1], i2 = esrc[j + 2], i3 = esrc[j + 3];
        const short* p0 = Xsrc + (size_t)i0 * HD + ksub;
        const short* p1 = Xsrc + (size_t)i1 * HD + ksub;
        const short* p2 = Xsrc + (size_t)i2 * HD + ksub;
        const short* p3 = Xsrc + (size_t)i3 * HD + ksub;
        short8 v0[4], v1[4], v2[4], v3[4];
#pragma unroll
        for (int kb = 0; kb < 4; ++kb) {
            v0[kb] = *(const short8*)(p0 + kb * 32);
            v1[kb] = *(const short8*)(p1 + kb * 32);
            v2[kb] = *(const short8*)(p2 + kb * 32);
            v3[kb] = *(const short8*)(p3 + kb * 32);
        }
#pragma unroll
        for (int kb = 0; kb < 4; ++kb)
#pragma unroll
            for (int i = 0; i < 8; ++i)
                macc[kb][i] += (bits2f(v0[kb][i]) + bits2f(v1[kb][i]))
                             + (bits2f(v2[kb][i]) + bits2f(v3[kb][i]));
    }
    for (; j < e; ++j) {
        const short* xp = Xsrc + (size_t)esrc[j] * HD + ksub;
#pragma unroll
        for (int kb = 0; kb < 4; ++kb) {
            short8 v = *(const short8*)(xp + kb * 32);
#pragma unroll
            for (int i = 0; i < 8; ++i) macc[kb][i] += bits2f(v[i]);
        }
    }
    const int d = e - s;
    const float inv = 1.f / (float)(d > 0 ? d : 1);
#pragma unroll
    for (int kb = 0; kb < 4; ++kb)
#pragma unroll
        for (int i = 0; i < 8; ++i) macc[kb][i] *= inv;
}

// ---- fold epilogue v2: LDS round-trip + second MFMA (replaces shfl butterfly) ----
// 1) leaky(acc+bias) -> bf16 into per-wave LDS tile [16][LROW] (pad -> <=2-way banks)
// 2) read back in A-frag layout (row=lane&15, k=(lane>>4)*8+j), one b128 per kb
// 3) MFMA with pre-packed folded weights (KBT=4), write Y bf16 directly.
template <int NT2>
__device__ __forceinline__ void fold_epi(const floatx4* acc8, const float* __restrict__ bias,
                                         const short* __restrict__ pFold,
                                         short* __restrict__ Y, int r0, int lane,
                                         short* my, int M) {
    const int colL = lane & 15;
    const int g = lane >> 4;
#pragma unroll
    for (int nt = 0; nt < 8; ++nt) {
        float bv = bias[nt * 16 + colL];
#pragma unroll
        for (int r = 0; r < 4; ++r) {
            float x = acc8[nt][r] + bv;
            x = (x >= 0.f) ? x : 0.01f * x;
            my[(g * 4 + r) * LROW + nt * 16 + colL] = f2bits(x);
        }
    }
    // same-wave LDS write->read: compiler inserts the lgkmcnt wait
    short8 af[4];
    const short* rp = my + colL * LROW + g * 8;
#pragma unroll
    for (int kb = 0; kb < 4; ++kb) af[kb] = *(const short8*)(rp + kb * 32);

    floatx4 a2[NT2];
#pragma unroll
    for (int nt2 = 0; nt2 < NT2; ++nt2) a2[nt2] = (floatx4){0.f, 0.f, 0.f, 0.f};
    const short8* wp = (const short8*)pFold + lane;
#pragma unroll
    for (int nt2 = 0; nt2 < NT2; ++nt2)
#pragma unroll
        for (int kb = 0; kb < 4; ++kb) {
            short8 b = wp[(nt2 * 4 + kb) * 64];
            a2[nt2] = __builtin_amdgcn_mfma_f32_16x16x32_bf16(af[kb], b, a2[nt2], 0, 0, 0);
        }

    const int rbase = r0 + g * 4;
#pragma unroll
    for (int nt2 = 0; nt2 < NT2; ++nt2)
#pragma unroll
        for (int r = 0; r < 4; ++r) {
            int row = rbase + r;
            if (row < M) Y[(size_t)row * (NT2 * 16) + nt2 * 16 + colL] = f2bits(a2[nt2][r]);
        }
}

// ================= merged SAGE layer-0 + folded layer-1 projection =================
// blocks [0, gU): user path (dual gather, KBT=12) -> YZ[NU][32]
// blocks [gU, gU+gI): item path (single gather + dense, KBT=8) -> YI[NI][16]
__global__ __launch_bounds__(256) void k_sage_all(
        const short* __restrict__ hu, const short* __restrict__ hi,
        const int* __restrict__ off_rates, const int* __restrict__ esrc_rates,
        const int* __restrict__ off_rated, const int* __restrict__ esrc_rated,
        const int* __restrict__ off_fol, const int* __restrict__ esrc_fol,
        const short* __restrict__ WpI, const float* __restrict__ biasI,
        const short* __restrict__ pYI,
        const short* __restrict__ WpU, const float* __restrict__ biasU,
        const short* __restrict__ pYU,
        short* __restrict__ YI, short* __restrict__ YZ, int gU) {
    __shared__ short stage[4 * 16 * LROW];
    const int lane = threadIdx.x & 63;
    const int wv = threadIdx.x >> 6;
    short* my = stage + wv * (16 * LROW);
    const int ksub = (lane >> 4) * 8;

    if ((int)blockIdx.x < gU) {
        // ---- user path ----
        const int r0 = blockIdx.x * 64 + wv * 16;
        int ar = r0 + (lane & 15);
        if (ar >= NU) ar = NU - 1;

        short8 afrag[12];
        {
            float macc[4][8];
            gather_mean(hi, off_rated, esrc_rated, ar, ksub, macc);
#pragma unroll
            for (int kb = 0; kb < 4; ++kb) {
                short8 f;
#pragma unroll
                for (int i = 0; i < 8; ++i) f[i] = f2bits(macc[kb][i]);
                afrag[kb] = f;
            }
            gather_mean(hu, off_fol, esrc_fol, ar, ksub, macc);
#pragma unroll
            for (int kb = 0; kb < 4; ++kb) {
                short8 f;
#pragma unroll
                for (int i = 0; i < 8; ++i) f[i] = f2bits(macc[kb][i]);
                afrag[4 + kb] = f;
            }
        }
        {
            const short* p = hu + (size_t)ar * HD + ksub;
#pragma unroll
            for (int kb = 0; kb < 4; ++kb) afrag[8 + kb] = *(const short8*)(p + kb * 32);
        }

        floatx4 acc[8];
#pragma unroll
        for (int nt = 0; nt < 8; ++nt) acc[nt] = (floatx4){0.f, 0.f, 0.f, 0.f};
        const short8* wp = (const short8*)WpU + lane;
#pragma unroll
        for (int nt = 0; nt < 8; ++nt)
#pragma unroll
            for (int kb = 0; kb < 12; ++kb) {
                short8 b = wp[(nt * 12 + kb) * 64];
                acc[nt] = __builtin_amdgcn_mfma_f32_16x16x32_bf16(afrag[kb], b, acc[nt], 0, 0, 0);
            }

        fold_epi<2>(acc, biasU, pYU, YZ, r0, lane, my, NU);
    } else {
        // ---- item path ----
        const int b = blockIdx.x - gU;
        const int r0 = b * 64 + wv * 16;
        int ar = r0 + (lane & 15);
        if (ar >= NI) ar = NI - 1;

        short8 afrag[8];
        {
            float macc[4][8];
            gather_mean(hu, off_rates, esrc_rates, ar, ksub, macc);
#pragma unroll
            for (int kb = 0; kb < 4; ++kb) {
                short8 f;
#pragma unroll
                for (int i = 0; i < 8; ++i) f[i] = f2bits(macc[kb][i]);
                afrag[kb] = f;
            }
            const short* p = hi + (size_t)ar * HD + ksub;
#pragma unroll
            for (int kb = 0; kb < 4; ++kb) afrag[4 + kb] = *(const short8*)(p + kb * 32);
        }

        floatx4 acc[8];
#pragma unroll
        for (int nt = 0; nt < 8; ++nt) acc[nt] = (floatx4){0.f, 0.f, 0.f, 0.f};
        const short8* wp = (const short8*)WpI + lane;
#pragma unroll
        for (int nt = 0; nt < 8; ++nt)
#pragma unroll
            for (int kb = 0; kb < 8; ++kb) {
                short8 b = wp[(nt * 8 + kb) * 64];
                acc[nt] = __builtin_amdgcn_mfma_f32_16x16x32_bf16(afrag[kb], b, acc[nt], 0, 0, 0);
            }

        fold_epi<1>(acc, biasI, pYI, YI, r0, lane, my, NI);
    }
}

// ================= plain MFMA GEMM (input projections): 32 rows/wave =================
template <int KB1, int NT>
__global__ __launch_bounds__(256) void k_mm(const float* __restrict__ A1,
                                            const short* __restrict__ Wp,
                                            const float* __restrict__ bias,
                                            short* __restrict__ C, int M) {
    constexpr int KBT = KB1;
    const int lane = threadIdx.x & 63;
    const int wv = threadIdx.x >> 6;
    const int r0 = blockIdx.x * 128 + wv * 32;

    const int ksub = (lane >> 4) * 8;
    short8 afrag[2][KBT];
#pragma unroll
    for (int h = 0; h < 2; ++h) {
        int ar = r0 + h * 16 + (lane & 15);
        if (ar >= M) ar = M - 1;
        const float* p = A1 + (size_t)ar * (KB1 * 32) + ksub;
#pragma unroll
        for (int kb = 0; kb < KB1; ++kb) {
            short8 f;
#pragma unroll
            for (int j = 0; j < 8; ++j) f[j] = f2bits(p[kb * 32 + j]);
            afrag[h][kb] = f;
        }
    }

    floatx4 acc[2][NT];
#pragma unroll
    for (int h = 0; h < 2; ++h)
#pragma unroll
        for (int nt = 0; nt < NT; ++nt) acc[h][nt] = (floatx4){0.f, 0.f, 0.f, 0.f};

    const short8* wp = (const short8*)Wp + lane;
#pragma unroll
    for (int nt = 0; nt < NT; ++nt)
#pragma unroll
        for (int kb = 0; kb < KBT; ++kb) {
            short8 b = wp[(nt * KBT + kb) * 64];
            acc[0][nt] = __builtin_amdgcn_mfma_f32_16x16x32_bf16(afrag[0][kb], b, acc[0][nt], 0, 0, 0);
            acc[1][nt] = __builtin_amdgcn_mfma_f32_16x16x32_bf16(afrag[1][kb], b, acc[1][nt], 0, 0, 0);
        }

    const int col = lane & 15;
#pragma unroll
    for (int h = 0; h < 2; ++h) {
        const int rbase = r0 + h * 16 + (lane >> 4) * 4;
#pragma unroll
        for (int nt = 0; nt < NT; ++nt) {
            float bv = bias ? bias[nt * 16 + col] : 0.f;
#pragma unroll
            for (int r = 0; r < 4; ++r) {
                int row = rbase + r;
                if (row < M)
                    C[(size_t)row * (NT * 16) + nt * 16 + col] = f2bits(acc[h][nt][r] + bv);
            }
        }
    }
}

// ================= final output =================
__global__ __launch_bounds__(256) void k_out(const short* __restrict__ YZ,
                                             const short* __restrict__ YI,
                                             const int* __restrict__ off_f,
                                             const int* __restrict__ esrc_f,
                                             const int* __restrict__ off_r,
                                             const int* __restrict__ esrc_r,
                                             const float* __restrict__ bias16,
                                             float* __restrict__ out, int N) {
    int t = threadIdx.x;
    int node = blockIdx.x * 128 + (t >> 1);
    int half = t & 1;
    if (node >= N) return;
    const int c0 = half * 8;

    float a[8] = {0.f, 0.f, 0.f, 0.f, 0.f, 0.f, 0.f, 0.f};
    {
        const int s = off_f[node], e = off_f[node + 1];
        int j = s;
        for (; j + 4 <= e; j += 4) {
            short8 v0 = *(const short8*)(YZ + (size_t)esrc_f[j] * 32 + c0);
            short8 v1 = *(const short8*)(YZ + (size_t)esrc_f[j + 1] * 32 + c0);
            short8 v2 = *(const short8*)(YZ + (size_t)esrc_f[j + 2] * 32 + c0);
            short8 v3 = *(const short8*)(YZ + (size_t)esrc_f[j + 3] * 32 + c0);
#pragma unroll
            for (int i = 0; i < 8; ++i)
                a[i] += (bits2f(v0[i]) + bits2f(v1[i])) + (bits2f(v2[i]) + bits2f(v3[i]));
        }
        for (; j < e; ++j) {
            short8 v = *(const short8*)(YZ + (size_t)esrc_f[j] * 32 + c0);
#pragma unroll
            for (int i = 0; i < 8; ++i) a[i] += bits2f(v[i]);
        }
        int d = e - s;
        float inv = 1.f / (float)(d > 0 ? d : 1);
#pragma unroll
        for (int i = 0; i < 8; ++i) a[i] *= inv;
    }
    {
        float b[8] = {0.f, 0.f, 0.f, 0.f, 0.f, 0.f, 0.f, 0.f};
        const int s = off_r[node], e = off_r[node + 1];
        int j = s;
        for (; j + 4 <= e; j += 4) {
            short8 v0 = *(const short8*)(YI + (size_t)esrc_r[j] * 16 + c0);
            short8 v1 = *(const short8*)(YI + (size_t)esrc_r[j + 1] * 16 + c0);
            short8 v2 = *(const short8*)(YI + (size_t)esrc_r[j + 2] * 16 + c0);
            short8 v3 = *(const short8*)(YI + (size_t)esrc_r[j + 3] * 16 + c0);
#pragma unroll
            for (int i = 0; i < 8; ++i)
                b[i] += (bits2f(v0[i]) + bits2f(v1[i])) + (bits2f(v2[i]) + bits2f(v3[i]));
        }
        for (; j < e; ++j) {
            short8 v = *(const short8*)(YI + (size_t)esrc_r[j] * 16 + c0);
#pragma unroll
            for (int i = 0; i < 8; ++i) b[i] += bits2f(v[i]);
        }
        int d = e - s;
        float inv = 1.f / (float)(d > 0 ? d : 1);
#pragma unroll
        for (int i = 0; i < 8; ++i) a[i] += b[i] * inv;
    }
    short8 z = *(const short8*)(YZ + (size_t)node * 32 + 16 + c0);
#pragma unroll
    for (int i = 0; i < 8; ++i)
        out[(size_t)node * 16 + c0 + i] = a[i] + bits2f(z[i]) + bias16[c0 + i];
}

// ================= launch =================
extern "C" void kernel_launch(void* const* d_in, const int* in_sizes, int n_in,
                              void* d_out, int out_size, void* d_ws, size_t ws_size,
                              hipStream_t stream) {
    const float* x_user    = (const float*)d_in[0];
    const float* x_item    = (const float*)d_in[1];
    const int* src_rates   = (const int*)d_in[2];
    const int* dst_rates   = (const int*)d_in[3];
    const int* src_rated   = (const int*)d_in[4];
    const int* dst_rated   = (const int*)d_in[5];
    const int* src_fol     = (const int*)d_in[6];
    const int* dst_fol     = (const int*)d_in[7];
    const float* W_in_user = (const float*)d_in[8];
    const float* b_in_user = (const float*)d_in[9];
    const float* W_in_item = (const float*)d_in[10];
    const float* b_in_item = (const float*)d_in[11];
    const float* Wl_rates  = (const float*)d_in[12];
    const float* bl_rates  = (const float*)d_in[13];
    const float* Wr_rates  = (const float*)d_in[14];
    const float* Wl_rated  = (const float*)d_in[15];
    const float* bl_rated  = (const float*)d_in[16];
    const float* Wr_rated  = (const float*)d_in[17];
    const float* Wl_fol    = (const float*)d_in[18];
    const float* bl_fol    = (const float*)d_in[19];
    const float* Wr_fol    = (const float*)d_in[20];
    const float* W_out     = (const float*)d_in[21];
    const float* b_out     = (const float*)d_in[22];
    float* out = (float*)d_out;

    char* w = (char*)d_ws;
    size_t used = 0;
    auto alloc = [&](size_t bytes) -> void* {
        void* p = w + used;
        used += (bytes + 255) & ~(size_t)255;
        return p;
    };
    short* hu_a = (short*)alloc((size_t)NU * HD * 2);
    short* hi_a = (short*)alloc((size_t)NI * HD * 2);
    short* YZ   = (short*)alloc((size_t)NU * 32 * 2);
    short* YI   = (short*)alloc((size_t)NI * 16 * 2);

    int* deg_rates  = (int*)alloc((size_t)NI * 4);
    int* off_rates  = (int*)alloc((size_t)(NI + 1) * 4);
    int* esrc_rates = (int*)alloc((size_t)NEDGE * 4);
    int* deg_rated  = (int*)alloc((size_t)NU * 4);
    int* off_rated  = (int*)alloc((size_t)(NU + 1) * 4);
    int* esrc_rated = (int*)alloc((size_t)NEDGE * 4);
    int* deg_fol    = (int*)alloc((size_t)NU * 4);
    int* off_fol    = (int*)alloc((size_t)(NU + 1) * 4);
    int* esrc_fol   = (int*)alloc((size_t)NEDGE * 4);
    int2* pairs     = (int2*)alloc((size_t)NEDGE * 8);
    int* bcur       = (int*)alloc(MAXBUK * 4);
    int* bsum = (int*)alloc(1024 * 4);
    int* boff = (int*)alloc(1024 * 4);

    short* pWu    = (short*)alloc(8 * 2 * 64 * 8 * 2);
    short* pWi    = (short*)alloc(8 * 4 * 64 * 8 * 2);
    short* pRates0 = (short*)alloc(8 * 8 * 64 * 8 * 2);
    short* pUser0  = (short*)alloc(8 * 12 * 64 * 8 * 2);   // [Wl_rated;Wl_fol;Wr_sum]
    float* WfU    = (float*)alloc(128 * 32 * 4);  // folded user [128][32] fp32
    float* WfI    = (float*)alloc(128 * 16 * 4);  // folded item [128][16] fp32
    short* pYU    = (short*)alloc(2 * 4 * 64 * 8 * 2);  // packed folded user (NT=2,KBT=4)
    short* pYI    = (short*)alloc(1 * 4 * 64 * 8 * 2);  // packed folded item (NT=1,KBT=4)
    float* bSum0  = (float*)alloc(128 * 4);
    float* bias16 = (float*)alloc(16 * 4);
    if (used > ws_size) return;   // diagnostic signature: output stays zero

    auto build_csr = [&](const int* dstA, const int* srcA, int N, int* deg, int* off,
                         int* esrc) {
        hipMemsetAsync(deg, 0, (size_t)N * 4, stream);
        k_hist<<<(NEDGE + 255) / 256, 256, 0, stream>>>(dstA, deg, NEDGE);
        int nb = (N + 1023) / 1024;
        k_block_sums<<<nb, 1024, 0, stream>>>(deg, bsum, N);
        k_scan_bsums<<<1, 1024, 0, stream>>>(bsum, boff, off, nb, N);
        k_scan_write<<<nb, 1024, 0, stream>>>(deg, boff, off, N);
        int nbuk = (N + BUK - 1) / BUK;
        k_initcur<<<1, 256, 0, stream>>>(off, bcur, nbuk, N);
        k_partA<<<(NEDGE + EPB - 1) / EPB, 256, 0, stream>>>(srcA, dstA, bcur, pairs, NEDGE);
        k_placeB<<<nbuk, 256, 0, stream>>>(pairs, off, esrc, N);
    };

    build_csr(dst_rates, src_rates, NI, deg_rates, off_rates, esrc_rates);
    build_csr(dst_rated, src_rated, NU, deg_rated, off_rated, esrc_rated);
    build_csr(dst_fol,   src_fol,   NU, deg_fol,   off_fol,   esrc_fol);

    // ---- weight packing ----
    k_pack<<<16, 64, 0, stream>>>(pWu, W_in_user, nullptr, nullptr, 64, 0, 128);
    k_pack<<<32, 64, 0, stream>>>(pWi, W_in_item, nullptr, nullptr, 128, 0, 128);
    k_pack<<<64, 64, 0, stream>>>(pRates0, Wl_rates, Wr_rates, nullptr, 128, 128, 128);
    k_pack3<<<96, 64, 0, stream>>>(pUser0, Wl_rated, Wl_fol, Wr_rated, Wr_fol);
    k_addbias<<<1, 128, 0, stream>>>(bSum0, bl_rated, bl_fol);
    // folded layer-1 weights (fp32 row-major), then pack to fragment order
    k_foldW<<<128, 16, 0, stream>>>(WfU, Wl_fol + HH,   nullptr,     W_out, 0, 32);
    k_foldW<<<128, 16, 0, stream>>>(WfU, Wr_rated + HH, Wr_fol + HH, W_out, 16, 32);
    k_foldW<<<128, 16, 0, stream>>>(WfI, Wl_rated + HH, nullptr,     W_out, 0, 16);
    k_pack<<<8, 64, 0, stream>>>(pYU, WfU, nullptr, nullptr, 128, 0, 32);
    k_pack<<<4, 64, 0, stream>>>(pYI, WfI, nullptr, nullptr, 128, 0, 16);
    k_bfold<<<1, 16, 0, stream>>>(bias16, bl_rated + 128, bl_fol + 128, W_out, b_out);

    const int gU2 = (NU + 127) / 128;
    const int gI2 = (NI + 127) / 128;
    const int gU  = (NU + 63) / 64;    // 3125
    const int gI  = (NI + 63) / 64;    // 1563

    // ---- input projections (fp32 A) ----
    k_mm<2, 8><<<gU2, 256, 0, stream>>>(x_user, pWu, b_in_user, hu_a, NU);
    k_mm<4, 8><<<gI2, 256, 0, stream>>>(x_item, pWi, b_in_item, hi_a, NI);

    // ---- merged layer-0 SAGE + folded layer-1 projection (user blocks first) ----
    k_sage_all<<<gU + gI, 256, 0, stream>>>(
        hu_a, hi_a, off_rates, esrc_rates, off_rated, esrc_rated, off_fol, esrc_fol,
        pRates0, bl_rates, pYI, pUser0, bSum0, pYU, YI, YZ, gU);

    // ---- final: dual 16-dim gather-mean + residual + bias -> fp32 out ----
    k_out<<<(NU + 127) / 128, 256, 0, stream>>>(
        YZ, YI, off_fol, esrc_fol, off_rated, esrc_rated, bias16, out, NU);
}

// Round 11
// 444.761 us; speedup vs baseline: 2.4132x; 1.3786x over previous
//
#include <hip/hip_runtime.h>
#include <cstdint>

typedef short short8 __attribute__((ext_vector_type(8)));
typedef float floatx4 __attribute__((ext_vector_type(4)));

constexpr int NU = 200000;   // N_USER
constexpr int NI = 100000;   // N_ITEM
constexpr int NEDGE = 1000000;
constexpr int HD = 128;
constexpr int HH = HD * HD;
constexpr int BUK = 1024;    // nodes per bucket
constexpr int EPB = 4096;    // edges per partition block
constexpr int EPT = 16;      // edges per thread (256 thr)
constexpr int MAXBUK = 256;  // >= ceil(NU/BUK)=196
constexpr int NBLK = (NEDGE + EPB - 1) / EPB;   // 245
constexpr int NB_I = (NI + BUK - 1) / BUK;      // 98
constexpr int NB_U = (NU + BUK - 1) / BUK;      // 196
constexpr int LROW = 136;    // LDS row stride in shorts (128 + 8 pad)

// ---- bf16 bit helpers ----
__device__ __forceinline__ float bits2f(short s) {
    return __uint_as_float(((unsigned int)(unsigned short)s) << 16);
}
__device__ __forceinline__ short f2bits(float f) {
    unsigned int u = __float_as_uint(f);
    unsigned int lsb = (u >> 16) & 1u;
    u += 0x7fffu + lsb;   // round-to-nearest-even
    return (short)(u >> 16);
}

// ================= CSR build v3: contention-free count/scan/place =================
// stage 1: per-block bucket histograms (LDS only, plain global stores)
__global__ __launch_bounds__(256) void k_cnt3(const int* __restrict__ dst0,
                                              const int* __restrict__ dst1,
                                              const int* __restrict__ dst2,
                                              int* __restrict__ cnts) {
    __shared__ int cnt[MAXBUK];
    const int g = blockIdx.x / NBLK;
    const int blk = blockIdx.x % NBLK;
    const int* dst = (g == 0) ? dst0 : (g == 1) ? dst1 : dst2;
    int t = threadIdx.x;
    for (int b = t; b < MAXBUK; b += 256) cnt[b] = 0;
    __syncthreads();
    const int e0 = blk * EPB + t * EPT;
#pragma unroll
    for (int i = 0; i < EPT; ++i) {
        int e = e0 + i;
        if (e < NEDGE) atomicAdd(&cnt[dst[e] >> 10], 1);
    }
    __syncthreads();
    for (int b = t; b < MAXBUK; b += 256)
        cnts[(size_t)(g * NBLK + blk) * MAXBUK + b] = cnt[b];
}

// stage 2: per-(block,bucket) bases + bucket offsets (3 blocks, 256 thr = buckets)
__global__ __launch_bounds__(256) void k_bases3(const int* __restrict__ cnts,
                                                int* __restrict__ base,
                                                int* __restrict__ bbase,
                                                int* __restrict__ off0,
                                                int* __restrict__ off1,
                                                int* __restrict__ off2) {
    __shared__ int s[256];
    const int g = blockIdx.x;
    const int t = threadIdx.x;
    int tot = 0;
    for (int blk = 0; blk < NBLK; ++blk)
        tot += cnts[(size_t)(g * NBLK + blk) * MAXBUK + t];
    s[t] = tot;
    __syncthreads();
    for (int d = 1; d < 256; d <<= 1) {
        int u = (t >= d) ? s[t - d] : 0;
        __syncthreads();
        s[t] += u;
        __syncthreads();
    }
    int bb = s[t] - tot;                 // exclusive bucket offset
    bbase[g * 257 + t] = bb;
    if (t == 255) bbase[g * 257 + 256] = bb + tot;   // = NEDGE
    int run = bb;
    for (int blk = 0; blk < NBLK; ++blk) {
        size_t idx = (size_t)(g * NBLK + blk) * MAXBUK + t;
        base[idx] = run;
        run += cnts[idx];
    }
    if (t == 0) {
        if (g == 0) off0[NI] = NEDGE;
        else if (g == 1) off1[NU] = NEDGE;
        else off2[NU] = NEDGE;
    }
}

// stage 3: place packed pairs (src | local_dst<<18) using precomputed bases
__global__ __launch_bounds__(256) void k_part3(const int* __restrict__ src0,
                                               const int* __restrict__ dst0,
                                               const int* __restrict__ src1,
                                               const int* __restrict__ dst1,
                                               const int* __restrict__ src2,
                                               const int* __restrict__ dst2,
                                               const int* __restrict__ base,
                                               int* __restrict__ pairs) {
    __shared__ int cnt[MAXBUK];
    __shared__ int bas[MAXBUK];
    const int g = blockIdx.x / NBLK;
    const int blk = blockIdx.x % NBLK;
    const int* src = (g == 0) ? src0 : (g == 1) ? src1 : src2;
    const int* dst = (g == 0) ? dst0 : (g == 1) ? dst1 : dst2;
    int* pg = pairs + (size_t)g * NEDGE;
    int t = threadIdx.x;
    for (int b = t; b < MAXBUK; b += 256) cnt[b] = 0;
    __syncthreads();
    const int e0 = blk * EPB + t * EPT;
    int sv[EPT], dv[EPT], rk[EPT];
#pragma unroll
    for (int i = 0; i < EPT; ++i) {
        int e = e0 + i;
        bool ok = e < NEDGE;
        dv[i] = ok ? dst[e] : 0;
        sv[i] = ok ? src[e] : 0;
    }
#pragma unroll
    for (int i = 0; i < EPT; ++i)
        rk[i] = (e0 + i < NEDGE) ? atomicAdd(&cnt[dv[i] >> 10], 1) : 0;
    __syncthreads();
    for (int b = t; b < MAXBUK; b += 256)
        bas[b] = base[(size_t)(g * NBLK + blk) * MAXBUK + b];
    __syncthreads();
#pragma unroll
    for (int i = 0; i < EPT; ++i) {
        if (e0 + i < NEDGE)
            pg[bas[dv[i] >> 10] + rk[i]] = sv[i] | ((dv[i] & 1023) << 18);
    }
}

// stage 4: per-bucket node offsets (LDS count+scan) + final esrc placement
__global__ __launch_bounds__(256) void k_place3(const int* __restrict__ pairs,
                                                const int* __restrict__ bbase,
                                                int* __restrict__ off0, int* __restrict__ esrc0,
                                                int* __restrict__ off1, int* __restrict__ esrc1,
                                                int* __restrict__ off2, int* __restrict__ esrc2) {
    __shared__ int cnt[BUK];
    __shared__ int ts[256];
    int bi = blockIdx.x;
    int g, bloc, N;
    int* off;
    int* esrc;
    if (bi < NB_I) { g = 0; bloc = bi; N = NI; off = off0; esrc = esrc0; }
    else if (bi < NB_I + NB_U) { g = 1; bloc = bi - NB_I; N = NU; off = off1; esrc = esrc1; }
    else { g = 2; bloc = bi - NB_I - NB_U; N = NU; off = off2; esrc = esrc2; }
    const int* pg = pairs + (size_t)g * NEDGE;
    const int b0 = bbase[g * 257 + bloc];
    const int b1 = bbase[g * 257 + bloc + 1];
    const int t = threadIdx.x;
    for (int i = t; i < BUK; i += 256) cnt[i] = 0;
    __syncthreads();
    for (int j = b0 + t; j < b1; j += 256) atomicAdd(&cnt[pg[j] >> 18], 1);
    __syncthreads();
    const int idx = t * 4;
    int c0 = cnt[idx], c1 = cnt[idx + 1], c2 = cnt[idx + 2], c3 = cnt[idx + 3];
    int ssum = c0 + c1 + c2 + c3;
    ts[t] = ssum;
    __syncthreads();
    for (int d = 1; d < 256; d <<= 1) {
        int u = (t >= d) ? ts[t - d] : 0;
        __syncthreads();
        ts[t] += u;
        __syncthreads();
    }
    int o = b0 + ts[t] - ssum;           // exclusive prefix for this thread's 4 nodes
    const int n0 = bloc * BUK;
    int cc[4] = {c0, c1, c2, c3};
#pragma unroll
    for (int i = 0; i < 4; ++i) {
        int n = n0 + idx + i;
        if (n < N) off[n] = o;
        cnt[idx + i] = o;                // reuse as cursors
        o += cc[i];
    }
    __syncthreads();
    for (int j = b0 + t; j < b1; j += 256) {
        int p = pg[j];
        int pos = atomicAdd(&cnt[p >> 18], 1);
        esrc[pos] = p & 0x3FFFF;
    }
}

// ================= weight pack (fp32 -> bf16 fragment order) =================
__global__ void k_pack(short* __restrict__ dst, const float* __restrict__ A,
                       const float* __restrict__ B, const float* __restrict__ B2,
                       int KA, int KBr, int NCOL) {
    int l = threadIdx.x;
    int kbt = (KA + KBr) >> 5;
    int nt = blockIdx.x / kbt;
    int kb = blockIdx.x % kbt;
    int col = nt * 16 + (l & 15);
    int k0 = kb * 32 + (l >> 4) * 8;
    short8 o;
#pragma unroll
    for (int j = 0; j < 8; ++j) {
        int k = k0 + j;
        float f;
        if (k < KA) {
            f = A[(size_t)k * NCOL + col];
        } else {
            int k2 = k - KA;
            f = B[(size_t)k2 * NCOL + col];
            if (B2) f += B2[(size_t)k2 * NCOL + col];
        }
        o[j] = f2bits(f);
    }
    *(short8*)(dst + ((size_t)blockIdx.x * 64 + l) * 8) = o;
}

// 3-section pack: W2 = [A(128) ; B(128) ; C1+C2(128)], KBT=12, NCOL=128
__global__ void k_pack3(short* __restrict__ dst, const float* __restrict__ A,
                        const float* __restrict__ B, const float* __restrict__ C1,
                        const float* __restrict__ C2) {
    int l = threadIdx.x;
    constexpr int kbt = 12;
    int nt = blockIdx.x / kbt;
    int kb = blockIdx.x % kbt;
    int col = nt * 16 + (l & 15);
    int k0 = kb * 32 + (l >> 4) * 8;
    short8 o;
#pragma unroll
    for (int j = 0; j < 8; ++j) {
        int k = k0 + j;
        float f;
        if (k < 128) f = A[(size_t)k * 128 + col];
        else if (k < 256) f = B[(size_t)(k - 128) * 128 + col];
        else f = C1[(size_t)(k - 256) * 128 + col] + C2[(size_t)(k - 256) * 128 + col];
        o[j] = f2bits(f);
    }
    *(short8*)(dst + ((size_t)blockIdx.x * 64 + l) * 8) = o;
}

// folded weight (row-major fp32): dst[k][colOff+c] = sum_t (Wa(+Wb))[k][t] * Wo[t][c]
__global__ void k_foldW(float* __restrict__ dst, const float* __restrict__ Wa,
                        const float* __restrict__ Wb, const float* __restrict__ Wo,
                        int colOff, int NC) {
    int k = blockIdx.x;
    int c = threadIdx.x;
    float a = 0.f;
    for (int t = 0; t < 128; ++t) {
        float w = Wa[(size_t)k * 128 + t];
        if (Wb) w += Wb[(size_t)k * 128 + t];
        a += w * Wo[t * 16 + c];
    }
    dst[(size_t)k * NC + colOff + c] = a;
}

__global__ void k_bfold(float* __restrict__ dst, const float* __restrict__ bl1,
                        const float* __restrict__ bl2, const float* __restrict__ Wo,
                        const float* __restrict__ bo) {
    int c = threadIdx.x;
    float a = 0.f;
    for (int t = 0; t < 128; ++t) a += (bl1[t] + bl2[t]) * Wo[t * 16 + c];
    dst[c] = a + bo[c];
}

__global__ void k_addbias(float* __restrict__ dst, const float* __restrict__ a,
                          const float* __restrict__ b) {
    int i = threadIdx.x;
    dst[i] = a[i] + b[i];
}

// ---- shared gather-mean helper ----
__device__ __forceinline__ void gather_mean(const short* __restrict__ Xsrc,
                                            const int* __restrict__ off,
                                            const int* __restrict__ esrc,
                                            int ar, int ksub, float macc[4][8]) {
#pragma unroll
    for (int kb = 0; kb < 4; ++kb)
#pragma unroll
        for (int i = 0; i < 8; ++i) macc[kb][i] = 0.f;

    const int s = off[ar], e = off[ar + 1];
    int j = s;
    for (; j + 4 <= e; j += 4) {
        const int i0 = esrc[j], i1 = esrc[j + 1], i2 = esrc[j + 2], i3 = esrc[j + 3];
        const short* p0 = Xsrc + (size_t)i0 * HD + ksub;
        const short* p1 = Xsrc + (size_t)i1 * HD + ksub;
        const short* p2 = Xsrc + (size_t)i2 * HD + ksub;
        const short* p3 = Xsrc + (size_t)i3 * HD + ksub;
        short8 v0[4], v1[4], v2[4], v3[4];
#pragma unroll
        for (int kb = 0; kb < 4; ++kb) {
            v0[kb] = *(const short8*)(p0 + kb * 32);
            v1[kb] = *(const short8*)(p1 + kb * 32);
            v2[kb] = *(const short8*)(p2 + kb * 32);
            v3[kb] = *(const short8*)(p3 + kb * 32);
        }
#pragma unroll
        for (int kb = 0; kb < 4; ++kb)
#pragma unroll
            for (int i = 0; i < 8; ++i)
                macc[kb][i] += (bits2f(v0[kb][i]) + bits2f(v1[kb][i]))
                             + (bits2f(v2[kb][i]) + bits2f(v3[kb][i]));
    }
    for (; j < e; ++j) {
        const short* xp = Xsrc + (size_t)esrc[j] * HD + ksub;
#pragma unroll
        for (int kb = 0; kb < 4; ++kb) {
            short8 v = *(const short8*)(xp + kb * 32);
#pragma unroll
            for (int i = 0; i < 8; ++i) macc[kb][i] += bits2f(v[i]);
        }
    }
    const int d = e - s;
    const float inv = 1.f / (float)(d > 0 ? d : 1);
#pragma unroll
    for (int kb = 0; kb < 4; ++kb)
#pragma unroll
        for (int i = 0; i < 8; ++i) macc[kb][i] *= inv;
}

// ---- fold epilogue: LDS round-trip + second MFMA ----
template <int NT2>
__device__ __forceinline__ void fold_epi(const floatx4* acc8, const float* __restrict__ bias,
                                         const short* __restrict__ pFold,
                                         short* __restrict__ Y, int r0, int lane,
                                         short* my, int M) {
    const int colL = lane & 15;
    const int g = lane >> 4;
#pragma unroll
    for (int nt = 0; nt < 8; ++nt) {
        float bv = bias[nt * 16 + colL];
#pragma unroll
        for (int r = 0; r < 4; ++r) {
            float x = acc8[nt][r] + bv;
            x = (x >= 0.f) ? x : 0.01f * x;
            my[(g * 4 + r) * LROW + nt * 16 + colL] = f2bits(x);
        }
    }
    short8 af[4];
    const short* rp = my + colL * LROW + g * 8;
#pragma unroll
    for (int kb = 0; kb < 4; ++kb) af[kb] = *(const short8*)(rp + kb * 32);

    floatx4 a2[NT2];
#pragma unroll
    for (int nt2 = 0; nt2 < NT2; ++nt2) a2[nt2] = (floatx4){0.f, 0.f, 0.f, 0.f};
    const short8* wp = (const short8*)pFold + lane;
#pragma unroll
    for (int nt2 = 0; nt2 < NT2; ++nt2)
#pragma unroll
        for (int kb = 0; kb < 4; ++kb) {
            short8 b = wp[(nt2 * 4 + kb) * 64];
            a2[nt2] = __builtin_amdgcn_mfma_f32_16x16x32_bf16(af[kb], b, a2[nt2], 0, 0, 0);
        }

    const int rbase = r0 + g * 4;
#pragma unroll
    for (int nt2 = 0; nt2 < NT2; ++nt2)
#pragma unroll
        for (int r = 0; r < 4; ++r) {
            int row = rbase + r;
            if (row < M) Y[(size_t)row * (NT2 * 16) + nt2 * 16 + colL] = f2bits(a2[nt2][r]);
        }
}

// ================= merged SAGE layer-0 + folded layer-1 projection =================
__global__ __launch_bounds__(256) void k_sage_all(
        const short* __restrict__ hu, const short* __restrict__ hi,
        const int* __restrict__ off_rates, const int* __restrict__ esrc_rates,
        const int* __restrict__ off_rated, const int* __restrict__ esrc_rated,
        const int* __restrict__ off_fol, const int* __restrict__ esrc_fol,
        const short* __restrict__ WpI, const float* __restrict__ biasI,
        const short* __restrict__ pYI,
        const short* __restrict__ WpU, const float* __restrict__ biasU,
        const short* __restrict__ pYU,
        short* __restrict__ YI, short* __restrict__ YZ, int gU) {
    __shared__ short stage[4 * 16 * LROW];
    const int lane = threadIdx.x & 63;
    const int wv = threadIdx.x >> 6;
    short* my = stage + wv * (16 * LROW);
    const int ksub = (lane >> 4) * 8;

    if ((int)blockIdx.x < gU) {
        const int r0 = blockIdx.x * 64 + wv * 16;
        int ar = r0 + (lane & 15);
        if (ar >= NU) ar = NU - 1;

        short8 afrag[12];
        {
            float macc[4][8];
            gather_mean(hi, off_rated, esrc_rated, ar, ksub, macc);
#pragma unroll
            for (int kb = 0; kb < 4; ++kb) {
                short8 f;
#pragma unroll
                for (int i = 0; i < 8; ++i) f[i] = f2bits(macc[kb][i]);
                afrag[kb] = f;
            }
            gather_mean(hu, off_fol, esrc_fol, ar, ksub, macc);
#pragma unroll
            for (int kb = 0; kb < 4; ++kb) {
                short8 f;
#pragma unroll
                for (int i = 0; i < 8; ++i) f[i] = f2bits(macc[kb][i]);
                afrag[4 + kb] = f;
            }
        }
        {
            const short* p = hu + (size_t)ar * HD + ksub;
#pragma unroll
            for (int kb = 0; kb < 4; ++kb) afrag[8 + kb] = *(const short8*)(p + kb * 32);
        }

        floatx4 acc[8];
#pragma unroll
        for (int nt = 0; nt < 8; ++nt) acc[nt] = (floatx4){0.f, 0.f, 0.f, 0.f};
        const short8* wp = (const short8*)WpU + lane;
#pragma unroll
        for (int nt = 0; nt < 8; ++nt)
#pragma unroll
            for (int kb = 0; kb < 12; ++kb) {
                short8 b = wp[(nt * 12 + kb) * 64];
                acc[nt] = __builtin_amdgcn_mfma_f32_16x16x32_bf16(afrag[kb], b, acc[nt], 0, 0, 0);
            }

        fold_epi<2>(acc, biasU, pYU, YZ, r0, lane, my, NU);
    } else {
        const int b = blockIdx.x - gU;
        const int r0 = b * 64 + wv * 16;
        int ar = r0 + (lane & 15);
        if (ar >= NI) ar = NI - 1;

        short8 afrag[8];
        {
            float macc[4][8];
            gather_mean(hu, off_rates, esrc_rates, ar, ksub, macc);
#pragma unroll
            for (int kb = 0; kb < 4; ++kb) {
                short8 f;
#pragma unroll
                for (int i = 0; i < 8; ++i) f[i] = f2bits(macc[kb][i]);
                afrag[kb] = f;
            }
            const short* p = hi + (size_t)ar * HD + ksub;
#pragma unroll
            for (int kb = 0; kb < 4; ++kb) afrag[4 + kb] = *(const short8*)(p + kb * 32);
        }

        floatx4 acc[8];
#pragma unroll
        for (int nt = 0; nt < 8; ++nt) acc[nt] = (floatx4){0.f, 0.f, 0.f, 0.f};
        const short8* wp = (const short8*)WpI + lane;
#pragma unroll
        for (int nt = 0; nt < 8; ++nt)
#pragma unroll
            for (int kb = 0; kb < 8; ++kb) {
                short8 b = wp[(nt * 8 + kb) * 64];
                acc[nt] = __builtin_amdgcn_mfma_f32_16x16x32_bf16(afrag[kb], b, acc[nt], 0, 0, 0);
            }

        fold_epi<1>(acc, biasI, pYI, YI, r0, lane, my, NI);
    }
}

// ================= input projections, merged (32 rows/wave) =================
template <int KB1>
__device__ __forceinline__ void mm_body(int bid, const float* __restrict__ A1,
                                        const short* __restrict__ Wp,
                                        const float* __restrict__ bias,
                                        short* __restrict__ C, int M,
                                        int lane, int wv) {
    const int r0 = bid * 128 + wv * 32;
    const int ksub = (lane >> 4) * 8;
    short8 afrag[2][KB1];
#pragma unroll
    for (int h = 0; h < 2; ++h) {
        int ar = r0 + h * 16 + (lane & 15);
        if (ar >= M) ar = M - 1;
        const float* p = A1 + (size_t)ar * (KB1 * 32) + ksub;
#pragma unroll
        for (int kb = 0; kb < KB1; ++kb) {
            short8 f;
#pragma unroll
            for (int j = 0; j < 8; ++j) f[j] = f2bits(p[kb * 32 + j]);
            afrag[h][kb] = f;
        }
    }
    floatx4 acc[2][8];
#pragma unroll
    for (int h = 0; h < 2; ++h)
#pragma unroll
        for (int nt = 0; nt < 8; ++nt) acc[h][nt] = (floatx4){0.f, 0.f, 0.f, 0.f};
    const short8* wp = (const short8*)Wp + lane;
#pragma unroll
    for (int nt = 0; nt < 8; ++nt)
#pragma unroll
        for (int kb = 0; kb < KB1; ++kb) {
            short8 b = wp[(nt * KB1 + kb) * 64];
            acc[0][nt] = __builtin_amdgcn_mfma_f32_16x16x32_bf16(afrag[0][kb], b, acc[0][nt], 0, 0, 0);
            acc[1][nt] = __builtin_amdgcn_mfma_f32_16x16x32_bf16(afrag[1][kb], b, acc[1][nt], 0, 0, 0);
        }
    const int col = lane & 15;
#pragma unroll
    for (int h = 0; h < 2; ++h) {
        const int rbase = r0 + h * 16 + (lane >> 4) * 4;
#pragma unroll
        for (int nt = 0; nt < 8; ++nt) {
            float bv = bias[nt * 16 + col];
#pragma unroll
            for (int r = 0; r < 4; ++r) {
                int row = rbase + r;
                if (row < M)
                    C[(size_t)row * 128 + nt * 16 + col] = f2bits(acc[h][nt][r] + bv);
            }
        }
    }
}

__global__ __launch_bounds__(256) void k_mm2(const float* __restrict__ xu,
                                             const short* __restrict__ pWu,
                                             const float* __restrict__ bu,
                                             short* __restrict__ hu,
                                             const float* __restrict__ xi,
                                             const short* __restrict__ pWi,
                                             const float* __restrict__ bi,
                                             short* __restrict__ hi, int gU2) {
    const int lane = threadIdx.x & 63;
    const int wv = threadIdx.x >> 6;
    if ((int)blockIdx.x < gU2)
        mm_body<2>(blockIdx.x, xu, pWu, bu, hu, NU, lane, wv);
    else
        mm_body<4>(blockIdx.x - gU2, xi, pWi, bi, hi, NI, lane, wv);
}

// ================= final output =================
__global__ __launch_bounds__(256) void k_out(const short* __restrict__ YZ,
                                             const short* __restrict__ YI,
                                             const int* __restrict__ off_f,
                                             const int* __restrict__ esrc_f,
                                             const int* __restrict__ off_r,
                                             const int* __restrict__ esrc_r,
                                             const float* __restrict__ bias16,
                                             float* __restrict__ out, int N) {
    int t = threadIdx.x;
    int node = blockIdx.x * 128 + (t >> 1);
    int half = t & 1;
    if (node >= N) return;
    const int c0 = half * 8;

    float a[8] = {0.f, 0.f, 0.f, 0.f, 0.f, 0.f, 0.f, 0.f};
    {
        const int s = off_f[node], e = off_f[node + 1];
        int j = s;
        for (; j + 4 <= e; j += 4) {
            short8 v0 = *(const short8*)(YZ + (size_t)esrc_f[j] * 32 + c0);
            short8 v1 = *(const short8*)(YZ + (size_t)esrc_f[j + 1] * 32 + c0);
            short8 v2 = *(const short8*)(YZ + (size_t)esrc_f[j + 2] * 32 + c0);
            short8 v3 = *(const short8*)(YZ + (size_t)esrc_f[j + 3] * 32 + c0);
#pragma unroll
            for (int i = 0; i < 8; ++i)
                a[i] += (bits2f(v0[i]) + bits2f(v1[i])) + (bits2f(v2[i]) + bits2f(v3[i]));
        }
        for (; j < e; ++j) {
            short8 v = *(const short8*)(YZ + (size_t)esrc_f[j] * 32 + c0);
#pragma unroll
            for (int i = 0; i < 8; ++i) a[i] += bits2f(v[i]);
        }
        int d = e - s;
        float inv = 1.f / (float)(d > 0 ? d : 1);
#pragma unroll
        for (int i = 0; i < 8; ++i) a[i] *= inv;
    }
    {
        float b[8] = {0.f, 0.f, 0.f, 0.f, 0.f, 0.f, 0.f, 0.f};
        const int s = off_r[node], e = off_r[node + 1];
        int j = s;
        for (; j + 4 <= e; j += 4) {
            short8 v0 = *(const short8*)(YI + (size_t)esrc_r[j] * 16 + c0);
            short8 v1 = *(const short8*)(YI + (size_t)esrc_r[j + 1] * 16 + c0);
            short8 v2 = *(const short8*)(YI + (size_t)esrc_r[j + 2] * 16 + c0);
            short8 v3 = *(const short8*)(YI + (size_t)esrc_r[j + 3] * 16 + c0);
#pragma unroll
            for (int i = 0; i < 8; ++i)
                b[i] += (bits2f(v0[i]) + bits2f(v1[i])) + (bits2f(v2[i]) + bits2f(v3[i]));
        }
        for (; j < e; ++j) {
            short8 v = *(const short8*)(YI + (size_t)esrc_r[j] * 16 + c0);
#pragma unroll
            for (int i = 0; i < 8; ++i) b[i] += bits2f(v[i]);
        }
        int d = e - s;
        float inv = 1.f / (float)(d > 0 ? d : 1);
#pragma unroll
        for (int i = 0; i < 8; ++i) a[i] += b[i] * inv;
    }
    short8 z = *(const short8*)(YZ + (size_t)node * 32 + 16 + c0);
#pragma unroll
    for (int i = 0; i < 8; ++i)
        out[(size_t)node * 16 + c0 + i] = a[i] + bits2f(z[i]) + bias16[c0 + i];
}

// ================= launch =================
extern "C" void kernel_launch(void* const* d_in, const int* in_sizes, int n_in,
                              void* d_out, int out_size, void* d_ws, size_t ws_size,
                              hipStream_t stream) {
    const float* x_user    = (const float*)d_in[0];
    const float* x_item    = (const float*)d_in[1];
    const int* src_rates   = (const int*)d_in[2];
    const int* dst_rates   = (const int*)d_in[3];
    const int* src_rated   = (const int*)d_in[4];
    const int* dst_rated   = (const int*)d_in[5];
    const int* src_fol     = (const int*)d_in[6];
    const int* dst_fol     = (const int*)d_in[7];
    const float* W_in_user = (const float*)d_in[8];
    const float* b_in_user = (const float*)d_in[9];
    const float* W_in_item = (const float*)d_in[10];
    const float* b_in_item = (const float*)d_in[11];
    const float* Wl_rates  = (const float*)d_in[12];
    const float* bl_rates  = (const float*)d_in[13];
    const float* Wr_rates  = (const float*)d_in[14];
    const float* Wl_rated  = (const float*)d_in[15];
    const float* bl_rated  = (const float*)d_in[16];
    const float* Wr_rated  = (const float*)d_in[17];
    const float* Wl_fol    = (const float*)d_in[18];
    const float* bl_fol    = (const float*)d_in[19];
    const float* Wr_fol    = (const float*)d_in[20];
    const float* W_out     = (const float*)d_in[21];
    const float* b_out     = (const float*)d_in[22];
    float* out = (float*)d_out;

    char* w = (char*)d_ws;
    size_t used = 0;
    auto alloc = [&](size_t bytes) -> void* {
        void* p = w + used;
        used += (bytes + 255) & ~(size_t)255;
        return p;
    };
    short* hu_a = (short*)alloc((size_t)NU * HD * 2);
    short* hi_a = (short*)alloc((size_t)NI * HD * 2);
    short* YZ   = (short*)alloc((size_t)NU * 32 * 2);
    short* YI   = (short*)alloc((size_t)NI * 16 * 2);

    int* off_rates  = (int*)alloc((size_t)(NI + 1) * 4);
    int* esrc_rates = (int*)alloc((size_t)NEDGE * 4);
    int* off_rated  = (int*)alloc((size_t)(NU + 1) * 4);
    int* esrc_rated = (int*)alloc((size_t)NEDGE * 4);
    int* off_fol    = (int*)alloc((size_t)(NU + 1) * 4);
    int* esrc_fol   = (int*)alloc((size_t)NEDGE * 4);
    int* pairs      = (int*)alloc((size_t)3 * NEDGE * 4);
    int* cnts       = (int*)alloc((size_t)3 * NBLK * MAXBUK * 4);
    int* base       = (int*)alloc((size_t)3 * NBLK * MAXBUK * 4);
    int* bbase      = (int*)alloc((size_t)3 * 257 * 4);

    short* pWu    = (short*)alloc(8 * 2 * 64 * 8 * 2);
    short* pWi    = (short*)alloc(8 * 4 * 64 * 8 * 2);
    short* pRates0 = (short*)alloc(8 * 8 * 64 * 8 * 2);
    short* pUser0  = (short*)alloc(8 * 12 * 64 * 8 * 2);
    float* WfU    = (float*)alloc(128 * 32 * 4);
    float* WfI    = (float*)alloc(128 * 16 * 4);
    short* pYU    = (short*)alloc(2 * 4 * 64 * 8 * 2);
    short* pYI    = (short*)alloc(1 * 4 * 64 * 8 * 2);
    float* bSum0  = (float*)alloc(128 * 4);
    float* bias16 = (float*)alloc(16 * 4);
    if (used > ws_size) return;   // diagnostic signature: output stays zero

    // ---- CSR build v3 (contention-free, all 3 graphs merged) ----
    k_cnt3<<<3 * NBLK, 256, 0, stream>>>(dst_rates, dst_rated, dst_fol, cnts);
    k_bases3<<<3, 256, 0, stream>>>(cnts, base, bbase, off_rates, off_rated, off_fol);
    k_part3<<<3 * NBLK, 256, 0, stream>>>(src_rates, dst_rates, src_rated, dst_rated,
                                          src_fol, dst_fol, base, pairs);
    k_place3<<<NB_I + 2 * NB_U, 256, 0, stream>>>(pairs, bbase,
                                                  off_rates, esrc_rates,
                                                  off_rated, esrc_rated,
                                                  off_fol, esrc_fol);

    // ---- weight packing ----
    k_pack<<<16, 64, 0, stream>>>(pWu, W_in_user, nullptr, nullptr, 64, 0, 128);
    k_pack<<<32, 64, 0, stream>>>(pWi, W_in_item, nullptr, nullptr, 128, 0, 128);
    k_pack<<<64, 64, 0, stream>>>(pRates0, Wl_rates, Wr_rates, nullptr, 128, 128, 128);
    k_pack3<<<96, 64, 0, stream>>>(pUser0, Wl_rated, Wl_fol, Wr_rated, Wr_fol);
    k_addbias<<<1, 128, 0, stream>>>(bSum0, bl_rated, bl_fol);
    k_foldW<<<128, 16, 0, stream>>>(WfU, Wl_fol + HH,   nullptr,     W_out, 0, 32);
    k_foldW<<<128, 16, 0, stream>>>(WfU, Wr_rated + HH, Wr_fol + HH, W_out, 16, 32);
    k_foldW<<<128, 16, 0, stream>>>(WfI, Wl_rated + HH, nullptr,     W_out, 0, 16);
    k_pack<<<8, 64, 0, stream>>>(pYU, WfU, nullptr, nullptr, 128, 0, 32);
    k_pack<<<4, 64, 0, stream>>>(pYI, WfI, nullptr, nullptr, 128, 0, 16);
    k_bfold<<<1, 16, 0, stream>>>(bias16, bl_rated + 128, bl_fol + 128, W_out, b_out);

    const int gU2 = (NU + 127) / 128;  // 1563
    const int gI2 = (NI + 127) / 128;  // 782
    const int gU  = (NU + 63) / 64;    // 3125
    const int gI  = (NI + 63) / 64;    // 1563

    // ---- input projections (merged) ----
    k_mm2<<<gU2 + gI2, 256, 0, stream>>>(x_user, pWu, b_in_user, hu_a,
                                         x_item, pWi, b_in_item, hi_a, gU2);

    // ---- merged layer-0 SAGE + folded layer-1 projection ----
    k_sage_all<<<gU + gI, 256, 0, stream>>>(
        hu_a, hi_a, off_rates, esrc_rates, off_rated, esrc_rated, off_fol, esrc_fol,
        pRates0, bl_rates, pYI, pUser0, bSum0, pYU, YI, YZ, gU);

    // ---- final: dual 16-dim gather-mean + residual + bias -> fp32 out ----
    k_out<<<(NU + 127) / 128, 256, 0, stream>>>(
        YZ, YI, off_fol, esrc_fol, off_rated, esrc_rated, bias16, out, NU);
}